// Round 6
// baseline (1551.375 us; speedup 1.0000x reference)
//
#include <hip/hip_runtime.h>
#include <hip/hip_bf16.h>
#include <stdint.h>

#define N_NODES 100000
#define N_EDGES 1600000
#define N_GRAPHS 512
#define IN_F 50
#define HID 128

typedef __attribute__((ext_vector_type(8))) short bf16x8;
typedef __attribute__((ext_vector_type(4))) float f32x4;

__device__ __forceinline__ float bf2f(unsigned short s) {
    return __uint_as_float(((unsigned)s) << 16);
}
__device__ __forceinline__ unsigned short f2bf(float f) {
    unsigned u = __float_as_uint(f);
    u = (u + 0x7FFFu + ((u >> 16) & 1u)) >> 16;   // round-to-nearest-even
    return (unsigned short)u;
}

// counts[g] = #nodes in graph g (batch is sorted) -- atomic-free binary search
__global__ void count_nodes(const int* __restrict__ batch, float* __restrict__ counts) {
    int g = blockIdx.x * blockDim.x + threadIdx.x;
    if (g >= N_GRAPHS) return;
    int lo = 0, hi = N_NODES;
    while (lo < hi) { int m = (lo + hi) >> 1; if (batch[m] < g) lo = m + 1; else hi = m; }
    int lo2 = lo, hi2 = N_NODES;
    while (lo2 < hi2) { int m = (lo2 + hi2) >> 1; if (batch[m] < g + 1) lo2 = m + 1; else hi2 = m; }
    counts[g] = (float)(lo2 - lo);
}

// ---------------- CSR build ----------------
__global__ void deg_hist(const int* __restrict__ dst, int* __restrict__ deg) {
    int gid = blockIdx.x * blockDim.x + threadIdx.x;
    int stride = gridDim.x * blockDim.x;
    for (int e = gid; e < N_EDGES; e += stride) atomicAdd(&deg[dst[e]], 1);
}

// -------- 3-phase grid-wide exclusive scan of deg[100000] --------
#define SCAN_BLOCKS ((N_NODES + 1023) / 1024)   // 98

__global__ __launch_bounds__(256) void scan_phase1(const int* __restrict__ deg,
                                                   int* __restrict__ blocksum) {
    __shared__ int red[256];
    int b = blockIdx.x, t = threadIdx.x;
    int base = b * 1024 + t * 4;
    int s = 0;
#pragma unroll
    for (int i = 0; i < 4; i++) { int idx = base + i; if (idx < N_NODES) s += deg[idx]; }
    red[t] = s;
    __syncthreads();
    for (int off = 128; off > 0; off >>= 1) {
        if (t < off) red[t] += red[t + off];
        __syncthreads();
    }
    if (t == 0) blocksum[b] = red[0];
}

__global__ __launch_bounds__(128) void scan_phase2(const int* __restrict__ blocksum,
                                                   int* __restrict__ blockoff) {
    __shared__ int v[SCAN_BLOCKS];
    int t = threadIdx.x;
    if (t < SCAN_BLOCKS) v[t] = blocksum[t];
    __syncthreads();
    if (t == 0) {
        int run = 0;
        for (int i = 0; i < SCAN_BLOCKS; i++) { blockoff[i] = run; run += v[i]; }
        blockoff[SCAN_BLOCKS] = run;
    }
}

__global__ __launch_bounds__(256) void scan_phase3(const int* __restrict__ deg,
                                                   const int* __restrict__ blockoff,
                                                   int* __restrict__ rowptr,
                                                   int* __restrict__ cursor) {
    __shared__ int red[256];
    int b = blockIdx.x, t = threadIdx.x;
    int base = b * 1024 + t * 4;
    int e[4];
    int s = 0;
#pragma unroll
    for (int i = 0; i < 4; i++) {
        int idx = base + i;
        e[i] = (idx < N_NODES) ? deg[idx] : 0;
        s += e[i];
    }
    red[t] = s;
    __syncthreads();
    for (int off = 1; off < 256; off <<= 1) {
        int u = (t >= off) ? red[t - off] : 0;
        __syncthreads();
        red[t] += u;
        __syncthreads();
    }
    int prefix = red[t] - s + blockoff[b];   // exclusive prefix of this thread's 4 elems
#pragma unroll
    for (int i = 0; i < 4; i++) {
        int idx = base + i;
        if (idx < N_NODES) { rowptr[idx] = prefix; cursor[idx] = prefix; prefix += e[i]; }
    }
    if (b == 0 && t == 0) rowptr[N_NODES] = blockoff[SCAN_BLOCKS];
}

__global__ void csr_fill(const int* __restrict__ src, const int* __restrict__ dst,
                         int* __restrict__ cursor, int* __restrict__ csr_src) {
    int gid = blockIdx.x * blockDim.x + threadIdx.x;
    int stride = gridDim.x * blockDim.x;
    for (int e = gid; e < N_EDGES; e += stride) {
        int d = dst[e];
        int p = atomicAdd(&cursor[d], 1);
        csr_src[p] = src[e];
    }
}

// ---------------- dtype prep ----------------
// all six weight matrices f32 -> bf16 in one launch (layer1 pair zero-padded 50->64)
__global__ __launch_bounds__(256) void wconv_all(
    const float* __restrict__ Wr1, const float* __restrict__ Wo1,
    const float* __restrict__ Wr2, const float* __restrict__ Wo2,
    const float* __restrict__ Wr3, const float* __restrict__ Wo3,
    unsigned short* __restrict__ o_r1, unsigned short* __restrict__ o_o1,
    unsigned short* __restrict__ o_r2, unsigned short* __restrict__ o_o2,
    unsigned short* __restrict__ o_r3, unsigned short* __restrict__ o_o3) {
    int idx = blockIdx.x * 256 + threadIdx.x;
    if (idx < 128 * 64) {
        int n = idx >> 6, k = idx & 63;
        unsigned short a = 0, b = 0;
        if (k < IN_F) { a = f2bf(Wr1[n * IN_F + k]); b = f2bf(Wo1[n * IN_F + k]); }
        o_r1[idx] = a; o_o1[idx] = b;
        return;
    }
    idx -= 128 * 64;
    if (idx < 128 * 128) {
        o_r2[idx] = f2bf(Wr2[idx]); o_o2[idx] = f2bf(Wo2[idx]);
        o_r3[idx] = f2bf(Wr3[idx]); o_o3[idx] = f2bf(Wo3[idx]);
    }
}

// x[100k][50] f32 -> xbf[100k][64] bf16 zero-padded
__global__ void xconv(const float* __restrict__ x, unsigned short* __restrict__ xbf) {
    int idx = blockIdx.x * 256 + threadIdx.x;
    if (idx >= N_NODES * 64) return;
    int n = idx >> 6, c = idx & 63;
    float v = (c < IN_F) ? x[(size_t)n * IN_F + c] : 0.f;
    xbf[idx] = f2bf(v);
}

// ---------------- pull aggregation (writes bf16) ----------------
// wave per node, F=50 f32 in -> bf16 [64] out (padded)
__global__ __launch_bounds__(256) void gather_f50(const float* __restrict__ x,
                                                  const int* __restrict__ rowptr,
                                                  const int* __restrict__ csr_src,
                                                  unsigned short* __restrict__ aggbf) {
    int gid = blockIdx.x * blockDim.x + threadIdx.x;
    int n = gid >> 6;
    int lane = threadIdx.x & 63;
    if (n >= N_NODES) return;
    int jb = rowptr[n], je = rowptr[n + 1];
    float acc = 0.f;
    int j = jb;
    for (; j + 1 < je; j += 2) {
        int s0 = csr_src[j], s1 = csr_src[j + 1];
        float v0 = 0.f, v1 = 0.f;
        if (lane < IN_F) { v0 = x[(size_t)s0 * IN_F + lane]; v1 = x[(size_t)s1 * IN_F + lane]; }
        acc += v0 + v1;
    }
    if (j < je) {
        int s0 = csr_src[j];
        if (lane < IN_F) acc += x[(size_t)s0 * IN_F + lane];
    }
    aggbf[(size_t)n * 64 + lane] = (lane < IN_F) ? f2bf(acc) : (unsigned short)0;
}

// wave per node, F=128 bf16 source: lane holds 2 features (one dword), bf16 out
__global__ __launch_bounds__(256) void gather_bf128(const unsigned short* __restrict__ h,
                                                    const int* __restrict__ rowptr,
                                                    const int* __restrict__ csr_src,
                                                    unsigned short* __restrict__ aggbf) {
    int gid = blockIdx.x * blockDim.x + threadIdx.x;
    int n = gid >> 6;
    int lane = threadIdx.x & 63;
    if (n >= N_NODES) return;
    int jb = rowptr[n], je = rowptr[n + 1];
    float acc0 = 0.f, acc1 = 0.f;
    const unsigned* hu = reinterpret_cast<const unsigned*>(h);
    int j = jb;
    for (; j + 1 < je; j += 2) {
        int s0 = csr_src[j], s1 = csr_src[j + 1];
        unsigned v0 = hu[(size_t)s0 * 64 + lane];
        unsigned v1 = hu[(size_t)s1 * 64 + lane];
        acc0 += bf2f((unsigned short)(v0 & 0xFFFF)) + bf2f((unsigned short)(v1 & 0xFFFF));
        acc1 += bf2f((unsigned short)(v0 >> 16)) + bf2f((unsigned short)(v1 >> 16));
    }
    if (j < je) {
        int s0 = csr_src[j];
        unsigned v0 = hu[(size_t)s0 * 64 + lane];
        acc0 += bf2f((unsigned short)(v0 & 0xFFFF));
        acc1 += bf2f((unsigned short)(v0 >> 16));
    }
    unsigned pk = (unsigned)f2bf(acc0) | ((unsigned)f2bf(acc1) << 16);
    reinterpret_cast<unsigned*>(aggbf)[(size_t)n * 64 + lane] = pk;
}

// ---------------- MFMA fused linear, v3: spill-free straight-line ----------------
// out = [relu](A1 @ B1^T + bias + A2 @ B2^T). A bf16 [M][K], B bf16 [128][K] (W layout).
// Block = 256 thr = 4 waves; BM=128 (wave owns 32 rows = 2 m-tiles). Weights staged in
// LDS with PITCH = K*2+16 (pad makes bank slot depend on weight row n -> uniform
// 8 lanes/16B slot = b128 data-movement minimum). Operands swapped in the MFMA:
// D = W_frag x A_frag -> lane&15 = node, (lane>>4)*4+reg = 4 CONSECUTIVE out cols
// -> uint2 contiguous stores. No lambdas, constexpr bounds, named acc arrays with
// compile-time indices only (R5's lambda-captured acc spilled to scratch: 349MB
// writes, VGPR=84, 930us).
// In-place safe (hout may alias A2): waves read only their own 32 rows, write same.
template <int K1, int K2, bool RELU, bool POOL>
__global__ __launch_bounds__(256) void mfma_linear(
    const unsigned short* __restrict__ A1, const unsigned short* __restrict__ A2,
    const unsigned short* __restrict__ B1, const unsigned short* __restrict__ B2,
    const float* __restrict__ bias, unsigned short* __restrict__ hout,
    const int* __restrict__ batch, float* __restrict__ pooled) {
    constexpr int P1 = K1 * 2 + 16;
    constexpr int P2 = K2 * 2 + 16;
    constexpr int PMAX = (P1 > P2 ? P1 : P2);
    __shared__ __align__(16) unsigned char ldsb[128 * PMAX];

    const int tid = threadIdx.x;
    const int lane = tid & 63;
    const int wave = tid >> 6;
    const int ar = lane & 15;          // node index within 16-tile (D col)
    const int kh = lane >> 4;          // k-chunk (8 elems) / D row-quad
    const int m0 = blockIdx.x * 128 + wave * 32;

    f32x4 acc0[8], acc1[8];
#pragma unroll
    for (int nt = 0; nt < 8; nt++) {
        acc0[nt] = (f32x4){0.f, 0.f, 0.f, 0.f};
        acc1[nt] = (f32x4){0.f, 0.f, 0.f, 0.f};
    }

    int r0 = m0 + ar;      if (r0 > N_NODES - 1) r0 = N_NODES - 1;
    int r1 = m0 + 16 + ar; if (r1 > N_NODES - 1) r1 = N_NODES - 1;

    // ---- stage B1 ----
    {
        constexpr int CPR = K1 / 8;
#pragma unroll
        for (int ci = 0; ci < 128 * CPR / 256; ci++) {
            int c = ci * 256 + tid;
            int n = c / CPR, slot = c - n * CPR;
            uint4 v = *reinterpret_cast<const uint4*>(B1 + n * K1 + slot * 8);
            *reinterpret_cast<uint4*>(&ldsb[n * P1 + slot * 16]) = v;
        }
    }
    __syncthreads();
    // ---- K-loop 1 ----
    {
        const unsigned short* a0p = A1 + (size_t)r0 * K1 + kh * 8;
        const unsigned short* a1p = A1 + (size_t)r1 * K1 + kh * 8;
#pragma unroll
        for (int ks = 0; ks < K1 / 32; ks++) {
            bf16x8 a0 = *reinterpret_cast<const bf16x8*>(a0p + ks * 32);
            bf16x8 a1 = *reinterpret_cast<const bf16x8*>(a1p + ks * 32);
#pragma unroll
            for (int nt = 0; nt < 8; nt++) {
                bf16x8 b = *reinterpret_cast<const bf16x8*>(
                    &ldsb[(nt * 16 + ar) * P1 + ks * 64 + kh * 16]);
                acc0[nt] = __builtin_amdgcn_mfma_f32_16x16x32_bf16(b, a0, acc0[nt], 0, 0, 0);
                acc1[nt] = __builtin_amdgcn_mfma_f32_16x16x32_bf16(b, a1, acc1[nt], 0, 0, 0);
            }
        }
    }
    __syncthreads();
    // ---- stage B2 ----
    {
        constexpr int CPR = K2 / 8;
#pragma unroll
        for (int ci = 0; ci < 128 * CPR / 256; ci++) {
            int c = ci * 256 + tid;
            int n = c / CPR, slot = c - n * CPR;
            uint4 v = *reinterpret_cast<const uint4*>(B2 + n * K2 + slot * 8);
            *reinterpret_cast<uint4*>(&ldsb[n * P2 + slot * 16]) = v;
        }
    }
    __syncthreads();
    // ---- K-loop 2 ----
    {
        const unsigned short* a0p = A2 + (size_t)r0 * K2 + kh * 8;
        const unsigned short* a1p = A2 + (size_t)r1 * K2 + kh * 8;
#pragma unroll
        for (int ks = 0; ks < K2 / 32; ks++) {
            bf16x8 a0 = *reinterpret_cast<const bf16x8*>(a0p + ks * 32);
            bf16x8 a1 = *reinterpret_cast<const bf16x8*>(a1p + ks * 32);
#pragma unroll
            for (int nt = 0; nt < 8; nt++) {
                bf16x8 b = *reinterpret_cast<const bf16x8*>(
                    &ldsb[(nt * 16 + ar) * P2 + ks * 64 + kh * 16]);
                acc0[nt] = __builtin_amdgcn_mfma_f32_16x16x32_bf16(b, a0, acc0[nt], 0, 0, 0);
                acc1[nt] = __builtin_amdgcn_mfma_f32_16x16x32_bf16(b, a1, acc1[nt], 0, 0, 0);
            }
        }
    }

    // ---- epilogue: lane holds 4 consecutive out-cols (kh*4..+3) per nt, per m-tile ----
    float4 bv[8];
#pragma unroll
    for (int nt = 0; nt < 8; nt++)
        bv[nt] = *reinterpret_cast<const float4*>(bias + nt * 16 + kh * 4);

    int node0 = m0 + ar;
    int node1 = m0 + 16 + ar;
    if (RELU) {
        if (node0 < N_NODES) {
#pragma unroll
            for (int nt = 0; nt < 8; nt++) {
                float v0 = fmaxf(acc0[nt][0] + bv[nt].x, 0.f);
                float v1 = fmaxf(acc0[nt][1] + bv[nt].y, 0.f);
                float v2 = fmaxf(acc0[nt][2] + bv[nt].z, 0.f);
                float v3 = fmaxf(acc0[nt][3] + bv[nt].w, 0.f);
                uint2 pk;
                pk.x = (unsigned)f2bf(v0) | ((unsigned)f2bf(v1) << 16);
                pk.y = (unsigned)f2bf(v2) | ((unsigned)f2bf(v3) << 16);
                *reinterpret_cast<uint2*>(hout + (size_t)node0 * HID + nt * 16 + kh * 4) = pk;
            }
        }
        if (node1 < N_NODES) {
#pragma unroll
            for (int nt = 0; nt < 8; nt++) {
                float v0 = fmaxf(acc1[nt][0] + bv[nt].x, 0.f);
                float v1 = fmaxf(acc1[nt][1] + bv[nt].y, 0.f);
                float v2 = fmaxf(acc1[nt][2] + bv[nt].z, 0.f);
                float v3 = fmaxf(acc1[nt][3] + bv[nt].w, 0.f);
                uint2 pk;
                pk.x = (unsigned)f2bf(v0) | ((unsigned)f2bf(v1) << 16);
                pk.y = (unsigned)f2bf(v2) | ((unsigned)f2bf(v3) << 16);
                *reinterpret_cast<uint2*>(hout + (size_t)node1 * HID + nt * 16 + kh * 4) = pk;
            }
        }
    }
    if (POOL) {
        if (node0 < N_NODES) {
            int g = batch[node0];
            float* pg = pooled + (size_t)g * HID + kh * 4;
#pragma unroll
            for (int nt = 0; nt < 8; nt++) {
                atomicAdd(pg + nt * 16 + 0, acc0[nt][0] + bv[nt].x);
                atomicAdd(pg + nt * 16 + 1, acc0[nt][1] + bv[nt].y);
                atomicAdd(pg + nt * 16 + 2, acc0[nt][2] + bv[nt].z);
                atomicAdd(pg + nt * 16 + 3, acc0[nt][3] + bv[nt].w);
            }
        }
        if (node1 < N_NODES) {
            int g = batch[node1];
            float* pg = pooled + (size_t)g * HID + kh * 4;
#pragma unroll
            for (int nt = 0; nt < 8; nt++) {
                atomicAdd(pg + nt * 16 + 0, acc1[nt][0] + bv[nt].x);
                atomicAdd(pg + nt * 16 + 1, acc1[nt][1] + bv[nt].y);
                atomicAdd(pg + nt * 16 + 2, acc1[nt][2] + bv[nt].z);
                atomicAdd(pg + nt * 16 + 3, acc1[nt][3] + bv[nt].w);
            }
        }
    }
}

__global__ void final_linear(const float* __restrict__ pooled, const float* __restrict__ counts,
                             const float* __restrict__ W_lin, const float* __restrict__ b_lin,
                             float* __restrict__ out) {
    __shared__ float p[HID];
    int g = blockIdx.x, tid = threadIdx.x;
    float c = fmaxf(counts[g], 1.f);
    p[tid] = pooled[(size_t)g * HID + tid] / c;
    __syncthreads();
    if (tid < 4) {
        float s = b_lin[tid];
#pragma unroll 8
        for (int k = 0; k < HID; k++) s += p[k] * W_lin[tid * HID + k];
        out[g * 4 + tid] = s;
    }
}

extern "C" void kernel_launch(void* const* d_in, const int* in_sizes, int n_in,
                              void* d_out, int out_size, void* d_ws, size_t ws_size,
                              hipStream_t stream) {
    (void)in_sizes; (void)n_in; (void)out_size; (void)ws_size;
    const float* x      = (const float*)d_in[0];
    const int*   ei     = (const int*)d_in[1];
    const int*   batch  = (const int*)d_in[2];
    const float* W_rel1 = (const float*)d_in[3];
    const float* b_rel1 = (const float*)d_in[4];
    const float* W_root1= (const float*)d_in[5];
    const float* W_rel2 = (const float*)d_in[6];
    const float* b_rel2 = (const float*)d_in[7];
    const float* W_root2= (const float*)d_in[8];
    const float* W_rel3 = (const float*)d_in[9];
    const float* b_rel3 = (const float*)d_in[10];
    const float* W_root3= (const float*)d_in[11];
    const float* W_lin  = (const float*)d_in[12];
    const float* b_lin  = (const float*)d_in[13];
    const int* src = ei;
    const int* dst = ei + N_EDGES;

    char* ws = (char*)d_ws;
    size_t off = 0;
    auto alloc = [&](size_t bytes) { void* p = ws + off; off += (bytes + 255) & ~(size_t)255; return p; };
    unsigned short* aggbf    = (unsigned short*)alloc((size_t)N_NODES * HID * 2); // 25.6 MB (layer1 uses [.][64] slice)
    unsigned short* h1       = (unsigned short*)alloc((size_t)N_NODES * HID * 2); // 25.6 MB (layers 2,3 in-place)
    unsigned short* xbf      = (unsigned short*)alloc((size_t)N_NODES * 64 * 2);  // 12.8 MB
    int*            deg      = (int*)alloc((size_t)N_NODES * 4);
    int*            rowptr   = (int*)alloc((size_t)(N_NODES + 1) * 4);
    int*            cursor   = (int*)alloc((size_t)N_NODES * 4);
    int*            csr_src  = (int*)alloc((size_t)N_EDGES * 4);                  // 6.4 MB
    int*            blocksum = (int*)alloc((size_t)(SCAN_BLOCKS + 1) * 4);
    int*            blockoff = (int*)alloc((size_t)(SCAN_BLOCKS + 1) * 4);
    unsigned short* Wb_rel1  = (unsigned short*)alloc(128 * 64 * 2);
    unsigned short* Wb_root1 = (unsigned short*)alloc(128 * 64 * 2);
    unsigned short* Wb_rel2  = (unsigned short*)alloc(128 * 128 * 2);
    unsigned short* Wb_root2 = (unsigned short*)alloc(128 * 128 * 2);
    unsigned short* Wb_rel3  = (unsigned short*)alloc(128 * 128 * 2);
    unsigned short* Wb_root3 = (unsigned short*)alloc(128 * 128 * 2);
    float*          pooled   = (float*)alloc((size_t)N_GRAPHS * HID * 4);
    float*          counts   = (float*)alloc(N_GRAPHS * 4);

    // ---- CSR build (parallel scan)
    hipMemsetAsync(deg, 0, (size_t)N_NODES * 4, stream);
    deg_hist<<<2048, 256, 0, stream>>>(dst, deg);
    scan_phase1<<<SCAN_BLOCKS, 256, 0, stream>>>(deg, blocksum);
    scan_phase2<<<1, 128, 0, stream>>>(blocksum, blockoff);
    scan_phase3<<<SCAN_BLOCKS, 256, 0, stream>>>(deg, blockoff, rowptr, cursor);
    csr_fill<<<2048, 256, 0, stream>>>(src, dst, cursor, csr_src);

    // ---- dtype prep
    wconv_all<<<(128 * 64 + 128 * 128 + 255) / 256, 256, 0, stream>>>(
        W_rel1, W_root1, W_rel2, W_root2, W_rel3, W_root3,
        Wb_rel1, Wb_root1, Wb_rel2, Wb_root2, Wb_rel3, Wb_root3);
    xconv<<<(N_NODES * 64 + 255) / 256, 256, 0, stream>>>(x, xbf);
    hipMemsetAsync(pooled, 0, (size_t)N_GRAPHS * HID * 4, stream);
    count_nodes<<<2, 256, 0, stream>>>(batch, counts);

    const int GATHER_BLOCKS = (N_NODES * 64 + 255) / 256;  // wave per node
    const int MFMA_BLOCKS = (N_NODES + 127) / 128;         // BM=128

    // ---- layer 1: pull-aggregate x (F=50), MFMA linears + relu -> h1 (bf16)
    gather_f50<<<GATHER_BLOCKS, 256, 0, stream>>>(x, rowptr, csr_src, aggbf);
    mfma_linear<64, 64, true, false><<<MFMA_BLOCKS, 256, 0, stream>>>(
        aggbf, xbf, Wb_rel1, Wb_root1, b_rel1, h1, nullptr, nullptr);

    // ---- layer 2: pull-aggregate h1 (F=128 bf16), MFMA linears + relu -> h1 (in-place)
    gather_bf128<<<GATHER_BLOCKS, 256, 0, stream>>>(h1, rowptr, csr_src, aggbf);
    mfma_linear<128, 128, true, false><<<MFMA_BLOCKS, 256, 0, stream>>>(
        aggbf, h1, Wb_rel2, Wb_root2, b_rel2, h1, nullptr, nullptr);

    // ---- layer 3: pull-aggregate h1, MFMA linears (no relu) + fused mean-pool
    gather_bf128<<<GATHER_BLOCKS, 256, 0, stream>>>(h1, rowptr, csr_src, aggbf);
    mfma_linear<128, 128, false, true><<<MFMA_BLOCKS, 256, 0, stream>>>(
        aggbf, h1, Wb_rel3, Wb_root3, b_rel3, nullptr, batch, pooled);

    final_linear<<<N_GRAPHS, HID, 0, stream>>>(pooled, counts, W_lin, b_lin, (float*)d_out);
}

// Round 7
// 696.036 us; speedup vs baseline: 2.2289x; 2.2289x over previous
//
#include <hip/hip_runtime.h>
#include <hip/hip_bf16.h>
#include <stdint.h>

#define N_NODES 100000
#define N_EDGES 1600000
#define N_GRAPHS 512
#define IN_F 50
#define HID 128

typedef __attribute__((ext_vector_type(8))) short bf16x8;
typedef __attribute__((ext_vector_type(4))) float f32x4;

__device__ __forceinline__ float bf2f(unsigned short s) {
    return __uint_as_float(((unsigned)s) << 16);
}
__device__ __forceinline__ unsigned short f2bf(float f) {
    unsigned u = __float_as_uint(f);
    u = (u + 0x7FFFu + ((u >> 16) & 1u)) >> 16;   // round-to-nearest-even
    return (unsigned short)u;
}

// gstart[g] = first node of graph g (batch is sorted); gstart[N_GRAPHS] = N_NODES
__global__ void graph_ranges(const int* __restrict__ batch, int* __restrict__ gstart) {
    int g = blockIdx.x * blockDim.x + threadIdx.x;
    if (g > N_GRAPHS) return;
    if (g == N_GRAPHS) { gstart[g] = N_NODES; return; }
    int lo = 0, hi = N_NODES;
    while (lo < hi) { int m = (lo + hi) >> 1; if (batch[m] < g) lo = m + 1; else hi = m; }
    gstart[g] = lo;
}

// ---------------- CSR build ----------------
__global__ void deg_hist(const int* __restrict__ dst, int* __restrict__ deg) {
    int gid = blockIdx.x * blockDim.x + threadIdx.x;
    int stride = gridDim.x * blockDim.x;
    for (int e = gid; e < N_EDGES; e += stride) atomicAdd(&deg[dst[e]], 1);
}

// -------- 3-phase grid-wide exclusive scan of deg[100000] --------
#define SCAN_BLOCKS ((N_NODES + 1023) / 1024)   // 98

__global__ __launch_bounds__(256) void scan_phase1(const int* __restrict__ deg,
                                                   int* __restrict__ blocksum) {
    __shared__ int red[256];
    int b = blockIdx.x, t = threadIdx.x;
    int base = b * 1024 + t * 4;
    int s = 0;
#pragma unroll
    for (int i = 0; i < 4; i++) { int idx = base + i; if (idx < N_NODES) s += deg[idx]; }
    red[t] = s;
    __syncthreads();
    for (int off = 128; off > 0; off >>= 1) {
        if (t < off) red[t] += red[t + off];
        __syncthreads();
    }
    if (t == 0) blocksum[b] = red[0];
}

__global__ __launch_bounds__(128) void scan_phase2(const int* __restrict__ blocksum,
                                                   int* __restrict__ blockoff) {
    __shared__ int v[SCAN_BLOCKS];
    int t = threadIdx.x;
    if (t < SCAN_BLOCKS) v[t] = blocksum[t];
    __syncthreads();
    if (t == 0) {
        int run = 0;
        for (int i = 0; i < SCAN_BLOCKS; i++) { blockoff[i] = run; run += v[i]; }
        blockoff[SCAN_BLOCKS] = run;
    }
}

__global__ __launch_bounds__(256) void scan_phase3(const int* __restrict__ deg,
                                                   const int* __restrict__ blockoff,
                                                   int* __restrict__ rowptr,
                                                   int* __restrict__ cursor) {
    __shared__ int red[256];
    int b = blockIdx.x, t = threadIdx.x;
    int base = b * 1024 + t * 4;
    int e[4];
    int s = 0;
#pragma unroll
    for (int i = 0; i < 4; i++) {
        int idx = base + i;
        e[i] = (idx < N_NODES) ? deg[idx] : 0;
        s += e[i];
    }
    red[t] = s;
    __syncthreads();
    for (int off = 1; off < 256; off <<= 1) {
        int u = (t >= off) ? red[t - off] : 0;
        __syncthreads();
        red[t] += u;
        __syncthreads();
    }
    int prefix = red[t] - s + blockoff[b];   // exclusive prefix of this thread's 4 elems
#pragma unroll
    for (int i = 0; i < 4; i++) {
        int idx = base + i;
        if (idx < N_NODES) { rowptr[idx] = prefix; cursor[idx] = prefix; prefix += e[i]; }
    }
    if (b == 0 && t == 0) rowptr[N_NODES] = blockoff[SCAN_BLOCKS];
}

__global__ void csr_fill(const int* __restrict__ src, const int* __restrict__ dst,
                         int* __restrict__ cursor, int* __restrict__ csr_src) {
    int gid = blockIdx.x * blockDim.x + threadIdx.x;
    int stride = gridDim.x * blockDim.x;
    for (int e = gid; e < N_EDGES; e += stride) {
        int d = dst[e];
        int p = atomicAdd(&cursor[d], 1);
        csr_src[p] = src[e];
    }
}

// ---------------- dtype prep ----------------
// all six weight matrices f32 -> bf16 in one launch (layer1 pair zero-padded 50->64)
__global__ __launch_bounds__(256) void wconv_all(
    const float* __restrict__ Wr1, const float* __restrict__ Wo1,
    const float* __restrict__ Wr2, const float* __restrict__ Wo2,
    const float* __restrict__ Wr3, const float* __restrict__ Wo3,
    unsigned short* __restrict__ o_r1, unsigned short* __restrict__ o_o1,
    unsigned short* __restrict__ o_r2, unsigned short* __restrict__ o_o2,
    unsigned short* __restrict__ o_r3, unsigned short* __restrict__ o_o3) {
    int idx = blockIdx.x * 256 + threadIdx.x;
    if (idx < 128 * 64) {
        int n = idx >> 6, k = idx & 63;
        unsigned short a = 0, b = 0;
        if (k < IN_F) { a = f2bf(Wr1[n * IN_F + k]); b = f2bf(Wo1[n * IN_F + k]); }
        o_r1[idx] = a; o_o1[idx] = b;
        return;
    }
    idx -= 128 * 64;
    if (idx < 128 * 128) {
        o_r2[idx] = f2bf(Wr2[idx]); o_o2[idx] = f2bf(Wo2[idx]);
        o_r3[idx] = f2bf(Wr3[idx]); o_o3[idx] = f2bf(Wo3[idx]);
    }
}

// x[100k][50] f32 -> xbf[100k][64] bf16 zero-padded
__global__ void xconv(const float* __restrict__ x, unsigned short* __restrict__ xbf) {
    int idx = blockIdx.x * 256 + threadIdx.x;
    if (idx >= N_NODES * 64) return;
    int n = idx >> 6, c = idx & 63;
    float v = (c < IN_F) ? x[(size_t)n * IN_F + c] : 0.f;
    xbf[idx] = f2bf(v);
}

// ---------------- pull aggregation (writes bf16) ----------------
// wave per node, F=50 f32 in -> bf16 [64] out (padded)
__global__ __launch_bounds__(256) void gather_f50(const float* __restrict__ x,
                                                  const int* __restrict__ rowptr,
                                                  const int* __restrict__ csr_src,
                                                  unsigned short* __restrict__ aggbf) {
    int gid = blockIdx.x * blockDim.x + threadIdx.x;
    int n = gid >> 6;
    int lane = threadIdx.x & 63;
    if (n >= N_NODES) return;
    int jb = rowptr[n], je = rowptr[n + 1];
    float acc = 0.f;
    int j = jb;
    for (; j + 1 < je; j += 2) {
        int s0 = csr_src[j], s1 = csr_src[j + 1];
        float v0 = 0.f, v1 = 0.f;
        if (lane < IN_F) { v0 = x[(size_t)s0 * IN_F + lane]; v1 = x[(size_t)s1 * IN_F + lane]; }
        acc += v0 + v1;
    }
    if (j < je) {
        int s0 = csr_src[j];
        if (lane < IN_F) acc += x[(size_t)s0 * IN_F + lane];
    }
    aggbf[(size_t)n * 64 + lane] = (lane < IN_F) ? f2bf(acc) : (unsigned short)0;
}

// wave per node, F=128 bf16 source: lane holds 2 features (one dword), bf16 out
__global__ __launch_bounds__(256) void gather_bf128(const unsigned short* __restrict__ h,
                                                    const int* __restrict__ rowptr,
                                                    const int* __restrict__ csr_src,
                                                    unsigned short* __restrict__ aggbf) {
    int gid = blockIdx.x * blockDim.x + threadIdx.x;
    int n = gid >> 6;
    int lane = threadIdx.x & 63;
    if (n >= N_NODES) return;
    int jb = rowptr[n], je = rowptr[n + 1];
    float acc0 = 0.f, acc1 = 0.f;
    const unsigned* hu = reinterpret_cast<const unsigned*>(h);
    int j = jb;
    for (; j + 1 < je; j += 2) {
        int s0 = csr_src[j], s1 = csr_src[j + 1];
        unsigned v0 = hu[(size_t)s0 * 64 + lane];
        unsigned v1 = hu[(size_t)s1 * 64 + lane];
        acc0 += bf2f((unsigned short)(v0 & 0xFFFF)) + bf2f((unsigned short)(v1 & 0xFFFF));
        acc1 += bf2f((unsigned short)(v0 >> 16)) + bf2f((unsigned short)(v1 >> 16));
    }
    if (j < je) {
        int s0 = csr_src[j];
        unsigned v0 = hu[(size_t)s0 * 64 + lane];
        acc0 += bf2f((unsigned short)(v0 & 0xFFFF));
        acc1 += bf2f((unsigned short)(v0 >> 16));
    }
    unsigned pk = (unsigned)f2bf(acc0) | ((unsigned)f2bf(acc1) << 16);
    reinterpret_cast<unsigned*>(aggbf)[(size_t)n * 64 + lane] = pk;
}

// ---------------- MFMA fused linear (no atomics) ----------------
// out = [relu](A1 @ B1^T + bias + A2 @ B2^T), stored bf16. A bf16 [M][K], B bf16 [128][K].
// Block = 256 thr = 4 waves; BM=128 (wave owns 32 rows = 2 m-tiles). Weights in LDS,
// PITCH = K*2+16. Operands swapped in MFMA: D = W_frag x A_frag -> lane&15 = node,
// (lane>>4)*4+reg = 4 consecutive out cols -> uint2 contiguous stores.
// In-place safe (hout may alias A1 or A2): all cross-wave (clamped-tail) reads are of
// discarded values; a wave's own-row reads complete before its epilogue writes.
template <int K1, int K2, bool RELU>
__global__ __launch_bounds__(256) void mfma_linear(
    const unsigned short* __restrict__ A1, const unsigned short* __restrict__ A2,
    const unsigned short* __restrict__ B1, const unsigned short* __restrict__ B2,
    const float* __restrict__ bias, unsigned short* __restrict__ hout) {
    constexpr int P1 = K1 * 2 + 16;
    constexpr int P2 = K2 * 2 + 16;
    constexpr int PMAX = (P1 > P2 ? P1 : P2);
    __shared__ __align__(16) unsigned char ldsb[128 * PMAX];

    const int tid = threadIdx.x;
    const int lane = tid & 63;
    const int wave = tid >> 6;
    const int ar = lane & 15;          // node index within 16-tile (D col)
    const int kh = lane >> 4;          // k-chunk (8 elems) / D row-quad
    const int m0 = blockIdx.x * 128 + wave * 32;

    f32x4 acc0[8], acc1[8];
#pragma unroll
    for (int nt = 0; nt < 8; nt++) {
        acc0[nt] = (f32x4){0.f, 0.f, 0.f, 0.f};
        acc1[nt] = (f32x4){0.f, 0.f, 0.f, 0.f};
    }

    int r0 = m0 + ar;      if (r0 > N_NODES - 1) r0 = N_NODES - 1;
    int r1 = m0 + 16 + ar; if (r1 > N_NODES - 1) r1 = N_NODES - 1;

    // ---- stage B1 ----
    {
        constexpr int CPR = K1 / 8;
#pragma unroll
        for (int ci = 0; ci < 128 * CPR / 256; ci++) {
            int c = ci * 256 + tid;
            int n = c / CPR, slot = c - n * CPR;
            uint4 v = *reinterpret_cast<const uint4*>(B1 + n * K1 + slot * 8);
            *reinterpret_cast<uint4*>(&ldsb[n * P1 + slot * 16]) = v;
        }
    }
    __syncthreads();
    // ---- K-loop 1 ----
    {
        const unsigned short* a0p = A1 + (size_t)r0 * K1 + kh * 8;
        const unsigned short* a1p = A1 + (size_t)r1 * K1 + kh * 8;
#pragma unroll
        for (int ks = 0; ks < K1 / 32; ks++) {
            bf16x8 a0 = *reinterpret_cast<const bf16x8*>(a0p + ks * 32);
            bf16x8 a1 = *reinterpret_cast<const bf16x8*>(a1p + ks * 32);
#pragma unroll
            for (int nt = 0; nt < 8; nt++) {
                bf16x8 b = *reinterpret_cast<const bf16x8*>(
                    &ldsb[(nt * 16 + ar) * P1 + ks * 64 + kh * 16]);
                acc0[nt] = __builtin_amdgcn_mfma_f32_16x16x32_bf16(b, a0, acc0[nt], 0, 0, 0);
                acc1[nt] = __builtin_amdgcn_mfma_f32_16x16x32_bf16(b, a1, acc1[nt], 0, 0, 0);
            }
        }
    }
    __syncthreads();
    // ---- stage B2 ----
    {
        constexpr int CPR = K2 / 8;
#pragma unroll
        for (int ci = 0; ci < 128 * CPR / 256; ci++) {
            int c = ci * 256 + tid;
            int n = c / CPR, slot = c - n * CPR;
            uint4 v = *reinterpret_cast<const uint4*>(B2 + n * K2 + slot * 8);
            *reinterpret_cast<uint4*>(&ldsb[n * P2 + slot * 16]) = v;
        }
    }
    __syncthreads();
    // ---- K-loop 2 ----
    {
        const unsigned short* a0p = A2 + (size_t)r0 * K2 + kh * 8;
        const unsigned short* a1p = A2 + (size_t)r1 * K2 + kh * 8;
#pragma unroll
        for (int ks = 0; ks < K2 / 32; ks++) {
            bf16x8 a0 = *reinterpret_cast<const bf16x8*>(a0p + ks * 32);
            bf16x8 a1 = *reinterpret_cast<const bf16x8*>(a1p + ks * 32);
#pragma unroll
            for (int nt = 0; nt < 8; nt++) {
                bf16x8 b = *reinterpret_cast<const bf16x8*>(
                    &ldsb[(nt * 16 + ar) * P2 + ks * 64 + kh * 16]);
                acc0[nt] = __builtin_amdgcn_mfma_f32_16x16x32_bf16(b, a0, acc0[nt], 0, 0, 0);
                acc1[nt] = __builtin_amdgcn_mfma_f32_16x16x32_bf16(b, a1, acc1[nt], 0, 0, 0);
            }
        }
    }

    // ---- epilogue: lane holds 4 consecutive out-cols (kh*4..+3) per nt, per m-tile ----
    float4 bv[8];
#pragma unroll
    for (int nt = 0; nt < 8; nt++)
        bv[nt] = *reinterpret_cast<const float4*>(bias + nt * 16 + kh * 4);

    int node0 = m0 + ar;
    int node1 = m0 + 16 + ar;
    if (node0 < N_NODES) {
#pragma unroll
        for (int nt = 0; nt < 8; nt++) {
            float v0 = acc0[nt][0] + bv[nt].x;
            float v1 = acc0[nt][1] + bv[nt].y;
            float v2 = acc0[nt][2] + bv[nt].z;
            float v3 = acc0[nt][3] + bv[nt].w;
            if (RELU) { v0 = fmaxf(v0, 0.f); v1 = fmaxf(v1, 0.f); v2 = fmaxf(v2, 0.f); v3 = fmaxf(v3, 0.f); }
            uint2 pk;
            pk.x = (unsigned)f2bf(v0) | ((unsigned)f2bf(v1) << 16);
            pk.y = (unsigned)f2bf(v2) | ((unsigned)f2bf(v3) << 16);
            *reinterpret_cast<uint2*>(hout + (size_t)node0 * HID + nt * 16 + kh * 4) = pk;
        }
    }
    if (node1 < N_NODES) {
#pragma unroll
        for (int nt = 0; nt < 8; nt++) {
            float v0 = acc1[nt][0] + bv[nt].x;
            float v1 = acc1[nt][1] + bv[nt].y;
            float v2 = acc1[nt][2] + bv[nt].z;
            float v3 = acc1[nt][3] + bv[nt].w;
            if (RELU) { v0 = fmaxf(v0, 0.f); v1 = fmaxf(v1, 0.f); v2 = fmaxf(v2, 0.f); v3 = fmaxf(v3, 0.f); }
            uint2 pk;
            pk.x = (unsigned)f2bf(v0) | ((unsigned)f2bf(v1) << 16);
            pk.y = (unsigned)f2bf(v2) | ((unsigned)f2bf(v3) << 16);
            *reinterpret_cast<uint2*>(hout + (size_t)node1 * HID + nt * 16 + kh * 4) = pk;
        }
    }
}

// ---------------- fused mean-pool + final linear (atomic-free) ----------------
// one 64-thread wave per graph; batch sorted -> contiguous node range [gstart[g], gstart[g+1]).
// lane holds 2 features (one dword of h3); coalesced 256B row reads.
__global__ __launch_bounds__(64) void pool_final(const unsigned short* __restrict__ h3,
                                                 const int* __restrict__ gstart,
                                                 const float* __restrict__ W_lin,
                                                 const float* __restrict__ b_lin,
                                                 float* __restrict__ out) {
    __shared__ float p[HID];
    int g = blockIdx.x, t = threadIdx.x;   // t in [0,64)
    int s0 = gstart[g], s1 = gstart[g + 1];
    const unsigned* h3u = reinterpret_cast<const unsigned*>(h3);
    float a0 = 0.f, a1 = 0.f;
    int n = s0;
    for (; n + 1 < s1; n += 2) {
        unsigned v0 = h3u[(size_t)n * 64 + t];
        unsigned v1 = h3u[(size_t)(n + 1) * 64 + t];
        a0 += bf2f((unsigned short)(v0 & 0xFFFF)) + bf2f((unsigned short)(v1 & 0xFFFF));
        a1 += bf2f((unsigned short)(v0 >> 16)) + bf2f((unsigned short)(v1 >> 16));
    }
    if (n < s1) {
        unsigned v0 = h3u[(size_t)n * 64 + t];
        a0 += bf2f((unsigned short)(v0 & 0xFFFF));
        a1 += bf2f((unsigned short)(v0 >> 16));
    }
    float c = fmaxf((float)(s1 - s0), 1.f);
    p[2 * t] = a0 / c;
    p[2 * t + 1] = a1 / c;
    __syncthreads();
    if (t < 4) {
        float s = b_lin[t];
#pragma unroll 8
        for (int k = 0; k < HID; k++) s += p[k] * W_lin[t * HID + k];
        out[g * 4 + t] = s;
    }
}

extern "C" void kernel_launch(void* const* d_in, const int* in_sizes, int n_in,
                              void* d_out, int out_size, void* d_ws, size_t ws_size,
                              hipStream_t stream) {
    (void)in_sizes; (void)n_in; (void)out_size; (void)ws_size;
    const float* x      = (const float*)d_in[0];
    const int*   ei     = (const int*)d_in[1];
    const int*   batch  = (const int*)d_in[2];
    const float* W_rel1 = (const float*)d_in[3];
    const float* b_rel1 = (const float*)d_in[4];
    const float* W_root1= (const float*)d_in[5];
    const float* W_rel2 = (const float*)d_in[6];
    const float* b_rel2 = (const float*)d_in[7];
    const float* W_root2= (const float*)d_in[8];
    const float* W_rel3 = (const float*)d_in[9];
    const float* b_rel3 = (const float*)d_in[10];
    const float* W_root3= (const float*)d_in[11];
    const float* W_lin  = (const float*)d_in[12];
    const float* b_lin  = (const float*)d_in[13];
    const int* src = ei;
    const int* dst = ei + N_EDGES;

    char* ws = (char*)d_ws;
    size_t off = 0;
    auto alloc = [&](size_t bytes) { void* p = ws + off; off += (bytes + 255) & ~(size_t)255; return p; };
    unsigned short* aggbf    = (unsigned short*)alloc((size_t)N_NODES * HID * 2); // 25.6 MB (layer1 [.][64] slice; layer3 output h3 in-place)
    unsigned short* h1       = (unsigned short*)alloc((size_t)N_NODES * HID * 2); // 25.6 MB (layer 2 in-place)
    unsigned short* xbf      = (unsigned short*)alloc((size_t)N_NODES * 64 * 2);  // 12.8 MB
    int*            deg      = (int*)alloc((size_t)N_NODES * 4);
    int*            rowptr   = (int*)alloc((size_t)(N_NODES + 1) * 4);
    int*            cursor   = (int*)alloc((size_t)N_NODES * 4);
    int*            csr_src  = (int*)alloc((size_t)N_EDGES * 4);                  // 6.4 MB
    int*            blocksum = (int*)alloc((size_t)(SCAN_BLOCKS + 1) * 4);
    int*            blockoff = (int*)alloc((size_t)(SCAN_BLOCKS + 1) * 4);
    int*            gstart   = (int*)alloc((size_t)(N_GRAPHS + 1) * 4);
    unsigned short* Wb_rel1  = (unsigned short*)alloc(128 * 64 * 2);
    unsigned short* Wb_root1 = (unsigned short*)alloc(128 * 64 * 2);
    unsigned short* Wb_rel2  = (unsigned short*)alloc(128 * 128 * 2);
    unsigned short* Wb_root2 = (unsigned short*)alloc(128 * 128 * 2);
    unsigned short* Wb_rel3  = (unsigned short*)alloc(128 * 128 * 2);
    unsigned short* Wb_root3 = (unsigned short*)alloc(128 * 128 * 2);

    // ---- CSR build (parallel scan)
    hipMemsetAsync(deg, 0, (size_t)N_NODES * 4, stream);
    deg_hist<<<2048, 256, 0, stream>>>(dst, deg);
    scan_phase1<<<SCAN_BLOCKS, 256, 0, stream>>>(deg, blocksum);
    scan_phase2<<<1, 128, 0, stream>>>(blocksum, blockoff);
    scan_phase3<<<SCAN_BLOCKS, 256, 0, stream>>>(deg, blockoff, rowptr, cursor);
    csr_fill<<<2048, 256, 0, stream>>>(src, dst, cursor, csr_src);

    // ---- dtype prep + graph ranges
    wconv_all<<<(128 * 64 + 128 * 128 + 255) / 256, 256, 0, stream>>>(
        W_rel1, W_root1, W_rel2, W_root2, W_rel3, W_root3,
        Wb_rel1, Wb_root1, Wb_rel2, Wb_root2, Wb_rel3, Wb_root3);
    xconv<<<(N_NODES * 64 + 255) / 256, 256, 0, stream>>>(x, xbf);
    graph_ranges<<<3, 256, 0, stream>>>(batch, gstart);

    const int GATHER_BLOCKS = (N_NODES * 64 + 255) / 256;  // wave per node
    const int MFMA_BLOCKS = (N_NODES + 127) / 128;         // BM=128

    // ---- layer 1: pull-aggregate x (F=50), MFMA linears + relu -> h1 (bf16)
    gather_f50<<<GATHER_BLOCKS, 256, 0, stream>>>(x, rowptr, csr_src, aggbf);
    mfma_linear<64, 64, true><<<MFMA_BLOCKS, 256, 0, stream>>>(
        aggbf, xbf, Wb_rel1, Wb_root1, b_rel1, h1);

    // ---- layer 2: pull-aggregate h1 (F=128 bf16), MFMA linears + relu -> h1 (in-place)
    gather_bf128<<<GATHER_BLOCKS, 256, 0, stream>>>(h1, rowptr, csr_src, aggbf);
    mfma_linear<128, 128, true><<<MFMA_BLOCKS, 256, 0, stream>>>(
        aggbf, h1, Wb_rel2, Wb_root2, b_rel2, h1);

    // ---- layer 3: pull-aggregate h1, MFMA linears (no relu) -> h3 (in-place over aggbf)
    gather_bf128<<<GATHER_BLOCKS, 256, 0, stream>>>(h1, rowptr, csr_src, aggbf);
    mfma_linear<128, 128, false><<<MFMA_BLOCKS, 256, 0, stream>>>(
        aggbf, h1, Wb_rel3, Wb_root3, b_rel3, aggbf);

    // ---- atomic-free mean-pool + final linear
    pool_final<<<N_GRAPHS, 64, 0, stream>>>(aggbf, gstart, W_lin, b_lin, (float*)d_out);
}

// Round 8
// 553.676 us; speedup vs baseline: 2.8020x; 1.2571x over previous
//
#include <hip/hip_runtime.h>
#include <hip/hip_bf16.h>
#include <stdint.h>

#define N_NODES 100000
#define N_EDGES 1600000
#define N_GRAPHS 512
#define IN_F 50
#define HID 128

#define NPART 8
#define PART_NODES ((N_NODES + NPART - 1) / NPART)   // 12500 (8*12500 = 100000 exactly)

typedef __attribute__((ext_vector_type(8))) short bf16x8;
typedef __attribute__((ext_vector_type(4))) float f32x4;

__device__ __forceinline__ float bf2f(unsigned short s) {
    return __uint_as_float(((unsigned)s) << 16);
}
__device__ __forceinline__ unsigned short f2bf(float f) {
    unsigned u = __float_as_uint(f);
    u = (u + 0x7FFFu + ((u >> 16) & 1u)) >> 16;   // round-to-nearest-even
    return (unsigned short)u;
}

// gstart[g] = first node of graph g (batch is sorted); gstart[N_GRAPHS] = N_NODES
__global__ void graph_ranges(const int* __restrict__ batch, int* __restrict__ gstart) {
    int g = blockIdx.x * blockDim.x + threadIdx.x;
    if (g > N_GRAPHS) return;
    if (g == N_GRAPHS) { gstart[g] = N_NODES; return; }
    int lo = 0, hi = N_NODES;
    while (lo < hi) { int m = (lo + hi) >> 1; if (batch[m] < g) lo = m + 1; else hi = m; }
    gstart[g] = lo;
}

// ---------------- CSR build (dst-partitioned for XCD write locality) ----------------
// 2048 blocks = 8 partitions x 256 edge-slices. blockIdx&7 -> partition (matches
// round-robin block->XCD dispatch), so each deg/csr_src line is written from one XCD's
// L2 only: line accumulates all its writes there, evicted once (was: 107MB WRITE_SIZE
// = every 4B store evicting its line; 120us).
__global__ __launch_bounds__(256) void deg_hist(const int* __restrict__ dst,
                                                int* __restrict__ deg) {
    int part = blockIdx.x & (NPART - 1);
    int plo = part * PART_NODES, phi = plo + PART_NODES;
    int base = (blockIdx.x >> 3) * 256 + threadIdx.x;
    int stride = (gridDim.x >> 3) * 256;
    for (int e = base; e < N_EDGES; e += stride) {
        int d = dst[e];
        if (d >= plo && d < phi) atomicAdd(&deg[d], 1);
    }
}

__global__ __launch_bounds__(256) void csr_fill(const int* __restrict__ src,
                                                const int* __restrict__ dst,
                                                int* __restrict__ cursor,
                                                int* __restrict__ csr_src) {
    int part = blockIdx.x & (NPART - 1);
    int plo = part * PART_NODES, phi = plo + PART_NODES;
    int base = (blockIdx.x >> 3) * 256 + threadIdx.x;
    int stride = (gridDim.x >> 3) * 256;
    for (int e = base; e < N_EDGES; e += stride) {
        int d = dst[e];
        if (d >= plo && d < phi) {
            int p = atomicAdd(&cursor[d], 1);
            csr_src[p] = src[e];
        }
    }
}

// -------- 3-phase grid-wide exclusive scan of deg[100000] --------
#define SCAN_BLOCKS ((N_NODES + 1023) / 1024)   // 98

__global__ __launch_bounds__(256) void scan_phase1(const int* __restrict__ deg,
                                                   int* __restrict__ blocksum) {
    __shared__ int red[256];
    int b = blockIdx.x, t = threadIdx.x;
    int base = b * 1024 + t * 4;
    int s = 0;
#pragma unroll
    for (int i = 0; i < 4; i++) { int idx = base + i; if (idx < N_NODES) s += deg[idx]; }
    red[t] = s;
    __syncthreads();
    for (int off = 128; off > 0; off >>= 1) {
        if (t < off) red[t] += red[t + off];
        __syncthreads();
    }
    if (t == 0) blocksum[b] = red[0];
}

__global__ __launch_bounds__(128) void scan_phase2(const int* __restrict__ blocksum,
                                                   int* __restrict__ blockoff) {
    __shared__ int v[SCAN_BLOCKS];
    int t = threadIdx.x;
    if (t < SCAN_BLOCKS) v[t] = blocksum[t];
    __syncthreads();
    if (t == 0) {
        int run = 0;
        for (int i = 0; i < SCAN_BLOCKS; i++) { blockoff[i] = run; run += v[i]; }
        blockoff[SCAN_BLOCKS] = run;
    }
}

__global__ __launch_bounds__(256) void scan_phase3(const int* __restrict__ deg,
                                                   const int* __restrict__ blockoff,
                                                   int* __restrict__ rowptr,
                                                   int* __restrict__ cursor) {
    __shared__ int red[256];
    int b = blockIdx.x, t = threadIdx.x;
    int base = b * 1024 + t * 4;
    int e[4];
    int s = 0;
#pragma unroll
    for (int i = 0; i < 4; i++) {
        int idx = base + i;
        e[i] = (idx < N_NODES) ? deg[idx] : 0;
        s += e[i];
    }
    red[t] = s;
    __syncthreads();
    for (int off = 1; off < 256; off <<= 1) {
        int u = (t >= off) ? red[t - off] : 0;
        __syncthreads();
        red[t] += u;
        __syncthreads();
    }
    int prefix = red[t] - s + blockoff[b];   // exclusive prefix of this thread's 4 elems
#pragma unroll
    for (int i = 0; i < 4; i++) {
        int idx = base + i;
        if (idx < N_NODES) { rowptr[idx] = prefix; cursor[idx] = prefix; prefix += e[i]; }
    }
    if (b == 0 && t == 0) rowptr[N_NODES] = blockoff[SCAN_BLOCKS];
}

// ---------------- dtype prep ----------------
// all six weight matrices f32 -> bf16 in one launch (layer1 pair zero-padded 50->64)
__global__ __launch_bounds__(256) void wconv_all(
    const float* __restrict__ Wr1, const float* __restrict__ Wo1,
    const float* __restrict__ Wr2, const float* __restrict__ Wo2,
    const float* __restrict__ Wr3, const float* __restrict__ Wo3,
    unsigned short* __restrict__ o_r1, unsigned short* __restrict__ o_o1,
    unsigned short* __restrict__ o_r2, unsigned short* __restrict__ o_o2,
    unsigned short* __restrict__ o_r3, unsigned short* __restrict__ o_o3) {
    int idx = blockIdx.x * 256 + threadIdx.x;
    if (idx < 128 * 64) {
        int n = idx >> 6, k = idx & 63;
        unsigned short a = 0, b = 0;
        if (k < IN_F) { a = f2bf(Wr1[n * IN_F + k]); b = f2bf(Wo1[n * IN_F + k]); }
        o_r1[idx] = a; o_o1[idx] = b;
        return;
    }
    idx -= 128 * 64;
    if (idx < 128 * 128) {
        o_r2[idx] = f2bf(Wr2[idx]); o_o2[idx] = f2bf(Wo2[idx]);
        o_r3[idx] = f2bf(Wr3[idx]); o_o3[idx] = f2bf(Wo3[idx]);
    }
}

// x[100k][50] f32 -> xbf[100k][64] bf16 zero-padded
__global__ void xconv(const float* __restrict__ x, unsigned short* __restrict__ xbf) {
    int idx = blockIdx.x * 256 + threadIdx.x;
    if (idx >= N_NODES * 64) return;
    int n = idx >> 6, c = idx & 63;
    float v = (c < IN_F) ? x[(size_t)n * IN_F + c] : 0.f;
    xbf[idx] = f2bf(v);
}

// ---------------- pull aggregation (writes bf16) ----------------
// wave per node, F=50 f32 in -> bf16 [64] out (padded); 4-edge unroll for load ILP
__global__ __launch_bounds__(256) void gather_f50(const float* __restrict__ x,
                                                  const int* __restrict__ rowptr,
                                                  const int* __restrict__ csr_src,
                                                  unsigned short* __restrict__ aggbf) {
    int gid = blockIdx.x * blockDim.x + threadIdx.x;
    int n = gid >> 6;
    int lane = threadIdx.x & 63;
    if (n >= N_NODES) return;
    int jb = rowptr[n], je = rowptr[n + 1];
    float acc = 0.f;
    int j = jb;
    if (lane < IN_F) {
        for (; j + 3 < je; j += 4) {
            int s0 = csr_src[j], s1 = csr_src[j + 1], s2 = csr_src[j + 2], s3 = csr_src[j + 3];
            float v0 = x[(size_t)s0 * IN_F + lane];
            float v1 = x[(size_t)s1 * IN_F + lane];
            float v2 = x[(size_t)s2 * IN_F + lane];
            float v3 = x[(size_t)s3 * IN_F + lane];
            acc += (v0 + v1) + (v2 + v3);
        }
        for (; j < je; j++) {
            int s0 = csr_src[j];
            acc += x[(size_t)s0 * IN_F + lane];
        }
    }
    aggbf[(size_t)n * 64 + lane] = (lane < IN_F) ? f2bf(acc) : (unsigned short)0;
}

// wave per node, F=128 bf16 source: lane holds 2 features (one dword); 4-edge unroll
__global__ __launch_bounds__(256) void gather_bf128(const unsigned short* __restrict__ h,
                                                    const int* __restrict__ rowptr,
                                                    const int* __restrict__ csr_src,
                                                    unsigned short* __restrict__ aggbf) {
    int gid = blockIdx.x * blockDim.x + threadIdx.x;
    int n = gid >> 6;
    int lane = threadIdx.x & 63;
    if (n >= N_NODES) return;
    int jb = rowptr[n], je = rowptr[n + 1];
    float acc0 = 0.f, acc1 = 0.f;
    const unsigned* hu = reinterpret_cast<const unsigned*>(h);
    int j = jb;
    for (; j + 3 < je; j += 4) {
        int s0 = csr_src[j], s1 = csr_src[j + 1], s2 = csr_src[j + 2], s3 = csr_src[j + 3];
        unsigned v0 = hu[(size_t)s0 * 64 + lane];
        unsigned v1 = hu[(size_t)s1 * 64 + lane];
        unsigned v2 = hu[(size_t)s2 * 64 + lane];
        unsigned v3 = hu[(size_t)s3 * 64 + lane];
        acc0 += (bf2f((unsigned short)(v0 & 0xFFFF)) + bf2f((unsigned short)(v1 & 0xFFFF)))
              + (bf2f((unsigned short)(v2 & 0xFFFF)) + bf2f((unsigned short)(v3 & 0xFFFF)));
        acc1 += (bf2f((unsigned short)(v0 >> 16)) + bf2f((unsigned short)(v1 >> 16)))
              + (bf2f((unsigned short)(v2 >> 16)) + bf2f((unsigned short)(v3 >> 16)));
    }
    for (; j < je; j++) {
        int s0 = csr_src[j];
        unsigned v0 = hu[(size_t)s0 * 64 + lane];
        acc0 += bf2f((unsigned short)(v0 & 0xFFFF));
        acc1 += bf2f((unsigned short)(v0 >> 16));
    }
    unsigned pk = (unsigned)f2bf(acc0) | ((unsigned)f2bf(acc1) << 16);
    reinterpret_cast<unsigned*>(aggbf)[(size_t)n * 64 + lane] = pk;
}

// ---------------- MFMA fused linear (no atomics) ----------------
// out = [relu](A1 @ B1^T + bias + A2 @ B2^T), stored bf16. A bf16 [M][K], B bf16 [128][K].
// Block = 256 thr = 4 waves; BM=128 (wave owns 32 rows = 2 m-tiles). Weights in LDS,
// PITCH = K*2+16. Operands swapped in MFMA: D = W_frag x A_frag -> lane&15 = node,
// (lane>>4)*4+reg = 4 consecutive out cols -> uint2 contiguous stores.
// In-place safe (hout may alias A1 or A2): all cross-wave (clamped-tail) reads are of
// discarded values; a wave's own-row reads complete before its epilogue writes.
template <int K1, int K2, bool RELU>
__global__ __launch_bounds__(256) void mfma_linear(
    const unsigned short* __restrict__ A1, const unsigned short* __restrict__ A2,
    const unsigned short* __restrict__ B1, const unsigned short* __restrict__ B2,
    const float* __restrict__ bias, unsigned short* __restrict__ hout) {
    constexpr int P1 = K1 * 2 + 16;
    constexpr int P2 = K2 * 2 + 16;
    constexpr int PMAX = (P1 > P2 ? P1 : P2);
    __shared__ __align__(16) unsigned char ldsb[128 * PMAX];

    const int tid = threadIdx.x;
    const int lane = tid & 63;
    const int wave = tid >> 6;
    const int ar = lane & 15;          // node index within 16-tile (D col)
    const int kh = lane >> 4;          // k-chunk (8 elems) / D row-quad
    const int m0 = blockIdx.x * 128 + wave * 32;

    f32x4 acc0[8], acc1[8];
#pragma unroll
    for (int nt = 0; nt < 8; nt++) {
        acc0[nt] = (f32x4){0.f, 0.f, 0.f, 0.f};
        acc1[nt] = (f32x4){0.f, 0.f, 0.f, 0.f};
    }

    int r0 = m0 + ar;      if (r0 > N_NODES - 1) r0 = N_NODES - 1;
    int r1 = m0 + 16 + ar; if (r1 > N_NODES - 1) r1 = N_NODES - 1;

    // ---- stage B1 ----
    {
        constexpr int CPR = K1 / 8;
#pragma unroll
        for (int ci = 0; ci < 128 * CPR / 256; ci++) {
            int c = ci * 256 + tid;
            int n = c / CPR, slot = c - n * CPR;
            uint4 v = *reinterpret_cast<const uint4*>(B1 + n * K1 + slot * 8);
            *reinterpret_cast<uint4*>(&ldsb[n * P1 + slot * 16]) = v;
        }
    }
    __syncthreads();
    // ---- K-loop 1 ----
    {
        const unsigned short* a0p = A1 + (size_t)r0 * K1 + kh * 8;
        const unsigned short* a1p = A1 + (size_t)r1 * K1 + kh * 8;
#pragma unroll
        for (int ks = 0; ks < K1 / 32; ks++) {
            bf16x8 a0 = *reinterpret_cast<const bf16x8*>(a0p + ks * 32);
            bf16x8 a1 = *reinterpret_cast<const bf16x8*>(a1p + ks * 32);
#pragma unroll
            for (int nt = 0; nt < 8; nt++) {
                bf16x8 b = *reinterpret_cast<const bf16x8*>(
                    &ldsb[(nt * 16 + ar) * P1 + ks * 64 + kh * 16]);
                acc0[nt] = __builtin_amdgcn_mfma_f32_16x16x32_bf16(b, a0, acc0[nt], 0, 0, 0);
                acc1[nt] = __builtin_amdgcn_mfma_f32_16x16x32_bf16(b, a1, acc1[nt], 0, 0, 0);
            }
        }
    }
    __syncthreads();
    // ---- stage B2 ----
    {
        constexpr int CPR = K2 / 8;
#pragma unroll
        for (int ci = 0; ci < 128 * CPR / 256; ci++) {
            int c = ci * 256 + tid;
            int n = c / CPR, slot = c - n * CPR;
            uint4 v = *reinterpret_cast<const uint4*>(B2 + n * K2 + slot * 8);
            *reinterpret_cast<uint4*>(&ldsb[n * P2 + slot * 16]) = v;
        }
    }
    __syncthreads();
    // ---- K-loop 2 ----
    {
        const unsigned short* a0p = A2 + (size_t)r0 * K2 + kh * 8;
        const unsigned short* a1p = A2 + (size_t)r1 * K2 + kh * 8;
#pragma unroll
        for (int ks = 0; ks < K2 / 32; ks++) {
            bf16x8 a0 = *reinterpret_cast<const bf16x8*>(a0p + ks * 32);
            bf16x8 a1 = *reinterpret_cast<const bf16x8*>(a1p + ks * 32);
#pragma unroll
            for (int nt = 0; nt < 8; nt++) {
                bf16x8 b = *reinterpret_cast<const bf16x8*>(
                    &ldsb[(nt * 16 + ar) * P2 + ks * 64 + kh * 16]);
                acc0[nt] = __builtin_amdgcn_mfma_f32_16x16x32_bf16(b, a0, acc0[nt], 0, 0, 0);
                acc1[nt] = __builtin_amdgcn_mfma_f32_16x16x32_bf16(b, a1, acc1[nt], 0, 0, 0);
            }
        }
    }

    // ---- epilogue: lane holds 4 consecutive out-cols (kh*4..+3) per nt, per m-tile ----
    float4 bv[8];
#pragma unroll
    for (int nt = 0; nt < 8; nt++)
        bv[nt] = *reinterpret_cast<const float4*>(bias + nt * 16 + kh * 4);

    int node0 = m0 + ar;
    int node1 = m0 + 16 + ar;
    if (node0 < N_NODES) {
#pragma unroll
        for (int nt = 0; nt < 8; nt++) {
            float v0 = acc0[nt][0] + bv[nt].x;
            float v1 = acc0[nt][1] + bv[nt].y;
            float v2 = acc0[nt][2] + bv[nt].z;
            float v3 = acc0[nt][3] + bv[nt].w;
            if (RELU) { v0 = fmaxf(v0, 0.f); v1 = fmaxf(v1, 0.f); v2 = fmaxf(v2, 0.f); v3 = fmaxf(v3, 0.f); }
            uint2 pk;
            pk.x = (unsigned)f2bf(v0) | ((unsigned)f2bf(v1) << 16);
            pk.y = (unsigned)f2bf(v2) | ((unsigned)f2bf(v3) << 16);
            *reinterpret_cast<uint2*>(hout + (size_t)node0 * HID + nt * 16 + kh * 4) = pk;
        }
    }
    if (node1 < N_NODES) {
#pragma unroll
        for (int nt = 0; nt < 8; nt++) {
            float v0 = acc1[nt][0] + bv[nt].x;
            float v1 = acc1[nt][1] + bv[nt].y;
            float v2 = acc1[nt][2] + bv[nt].z;
            float v3 = acc1[nt][3] + bv[nt].w;
            if (RELU) { v0 = fmaxf(v0, 0.f); v1 = fmaxf(v1, 0.f); v2 = fmaxf(v2, 0.f); v3 = fmaxf(v3, 0.f); }
            uint2 pk;
            pk.x = (unsigned)f2bf(v0) | ((unsigned)f2bf(v1) << 16);
            pk.y = (unsigned)f2bf(v2) | ((unsigned)f2bf(v3) << 16);
            *reinterpret_cast<uint2*>(hout + (size_t)node1 * HID + nt * 16 + kh * 4) = pk;
        }
    }
}

// ---------------- fused mean-pool + final linear (atomic-free) ----------------
// 256 threads = 4 waves per graph; wave w handles nodes s0+w, s0+w+4, ... (coalesced
// 256B row reads, 4 concurrent streams/block); LDS cross-wave reduce then tiny linear.
__global__ __launch_bounds__(256) void pool_final(const unsigned short* __restrict__ h3,
                                                  const int* __restrict__ gstart,
                                                  const float* __restrict__ W_lin,
                                                  const float* __restrict__ b_lin,
                                                  float* __restrict__ out) {
    __shared__ float pp[4][HID];
    int g = blockIdx.x, t = threadIdx.x;
    int wave = t >> 6, lane = t & 63;
    int s0 = gstart[g], s1 = gstart[g + 1];
    const unsigned* h3u = reinterpret_cast<const unsigned*>(h3);
    float a0 = 0.f, a1 = 0.f;
    for (int n = s0 + wave; n < s1; n += 4) {
        unsigned v = h3u[(size_t)n * 64 + lane];
        a0 += bf2f((unsigned short)(v & 0xFFFF));
        a1 += bf2f((unsigned short)(v >> 16));
    }
    pp[wave][2 * lane] = a0;
    pp[wave][2 * lane + 1] = a1;
    __syncthreads();
    if (wave == 0) {
        float c = fmaxf((float)(s1 - s0), 1.f);
        float r0 = ((pp[0][2 * lane] + pp[1][2 * lane]) + (pp[2][2 * lane] + pp[3][2 * lane])) / c;
        float r1 = ((pp[0][2 * lane + 1] + pp[1][2 * lane + 1]) + (pp[2][2 * lane + 1] + pp[3][2 * lane + 1])) / c;
        pp[0][2 * lane] = r0;
        pp[0][2 * lane + 1] = r1;
    }
    __syncthreads();
    if (t < 4) {
        float s = b_lin[t];
#pragma unroll 8
        for (int k = 0; k < HID; k++) s += pp[0][k] * W_lin[t * HID + k];
        out[g * 4 + t] = s;
    }
}

extern "C" void kernel_launch(void* const* d_in, const int* in_sizes, int n_in,
                              void* d_out, int out_size, void* d_ws, size_t ws_size,
                              hipStream_t stream) {
    (void)in_sizes; (void)n_in; (void)out_size; (void)ws_size;
    const float* x      = (const float*)d_in[0];
    const int*   ei     = (const int*)d_in[1];
    const int*   batch  = (const int*)d_in[2];
    const float* W_rel1 = (const float*)d_in[3];
    const float* b_rel1 = (const float*)d_in[4];
    const float* W_root1= (const float*)d_in[5];
    const float* W_rel2 = (const float*)d_in[6];
    const float* b_rel2 = (const float*)d_in[7];
    const float* W_root2= (const float*)d_in[8];
    const float* W_rel3 = (const float*)d_in[9];
    const float* b_rel3 = (const float*)d_in[10];
    const float* W_root3= (const float*)d_in[11];
    const float* W_lin  = (const float*)d_in[12];
    const float* b_lin  = (const float*)d_in[13];
    const int* src = ei;
    const int* dst = ei + N_EDGES;

    char* ws = (char*)d_ws;
    size_t off = 0;
    auto alloc = [&](size_t bytes) { void* p = ws + off; off += (bytes + 255) & ~(size_t)255; return p; };
    unsigned short* aggbf    = (unsigned short*)alloc((size_t)N_NODES * HID * 2); // 25.6 MB (layer1 [.][64] slice; layer3 output h3 in-place)
    unsigned short* h1       = (unsigned short*)alloc((size_t)N_NODES * HID * 2); // 25.6 MB (layer 2 in-place)
    unsigned short* xbf      = (unsigned short*)alloc((size_t)N_NODES * 64 * 2);  // 12.8 MB
    int*            deg      = (int*)alloc((size_t)N_NODES * 4);
    int*            rowptr   = (int*)alloc((size_t)(N_NODES + 1) * 4);
    int*            cursor   = (int*)alloc((size_t)N_NODES * 4);
    int*            csr_src  = (int*)alloc((size_t)N_EDGES * 4);                  // 6.4 MB
    int*            blocksum = (int*)alloc((size_t)(SCAN_BLOCKS + 1) * 4);
    int*            blockoff = (int*)alloc((size_t)(SCAN_BLOCKS + 1) * 4);
    int*            gstart   = (int*)alloc((size_t)(N_GRAPHS + 1) * 4);
    unsigned short* Wb_rel1  = (unsigned short*)alloc(128 * 64 * 2);
    unsigned short* Wb_root1 = (unsigned short*)alloc(128 * 64 * 2);
    unsigned short* Wb_rel2  = (unsigned short*)alloc(128 * 128 * 2);
    unsigned short* Wb_root2 = (unsigned short*)alloc(128 * 128 * 2);
    unsigned short* Wb_rel3  = (unsigned short*)alloc(128 * 128 * 2);
    unsigned short* Wb_root3 = (unsigned short*)alloc(128 * 128 * 2);

    // ---- CSR build (parallel scan; dst-partitioned hist/fill)
    hipMemsetAsync(deg, 0, (size_t)N_NODES * 4, stream);
    deg_hist<<<2048, 256, 0, stream>>>(dst, deg);
    scan_phase1<<<SCAN_BLOCKS, 256, 0, stream>>>(deg, blocksum);
    scan_phase2<<<1, 128, 0, stream>>>(blocksum, blockoff);
    scan_phase3<<<SCAN_BLOCKS, 256, 0, stream>>>(deg, blockoff, rowptr, cursor);
    csr_fill<<<2048, 256, 0, stream>>>(src, dst, cursor, csr_src);

    // ---- dtype prep + graph ranges
    wconv_all<<<(128 * 64 + 128 * 128 + 255) / 256, 256, 0, stream>>>(
        W_rel1, W_root1, W_rel2, W_root2, W_rel3, W_root3,
        Wb_rel1, Wb_root1, Wb_rel2, Wb_root2, Wb_rel3, Wb_root3);
    xconv<<<(N_NODES * 64 + 255) / 256, 256, 0, stream>>>(x, xbf);
    graph_ranges<<<3, 256, 0, stream>>>(batch, gstart);

    const int GATHER_BLOCKS = (N_NODES * 64 + 255) / 256;  // wave per node
    const int MFMA_BLOCKS = (N_NODES + 127) / 128;         // BM=128

    // ---- layer 1: pull-aggregate x (F=50), MFMA linears + relu -> h1 (bf16)
    gather_f50<<<GATHER_BLOCKS, 256, 0, stream>>>(x, rowptr, csr_src, aggbf);
    mfma_linear<64, 64, true><<<MFMA_BLOCKS, 256, 0, stream>>>(
        aggbf, xbf, Wb_rel1, Wb_root1, b_rel1, h1);

    // ---- layer 2: pull-aggregate h1 (F=128 bf16), MFMA linears + relu -> h1 (in-place)
    gather_bf128<<<GATHER_BLOCKS, 256, 0, stream>>>(h1, rowptr, csr_src, aggbf);
    mfma_linear<128, 128, true><<<MFMA_BLOCKS, 256, 0, stream>>>(
        aggbf, h1, Wb_rel2, Wb_root2, b_rel2, h1);

    // ---- layer 3: pull-aggregate h1, MFMA linears (no relu) -> h3 (in-place over aggbf)
    gather_bf128<<<GATHER_BLOCKS, 256, 0, stream>>>(h1, rowptr, csr_src, aggbf);
    mfma_linear<128, 128, false><<<MFMA_BLOCKS, 256, 0, stream>>>(
        aggbf, h1, Wb_rel3, Wb_root3, b_rel3, aggbf);

    // ---- atomic-free mean-pool + final linear
    pool_final<<<N_GRAPHS, 256, 0, stream>>>(aggbf, gstart, W_lin, b_lin, (float*)d_out);
}

// Round 9
// 492.468 us; speedup vs baseline: 3.1502x; 1.1243x over previous
//
#include <hip/hip_runtime.h>
#include <hip/hip_bf16.h>
#include <stdint.h>

#define N_NODES 100000
#define N_EDGES 1600000
#define N_GRAPHS 512
#define IN_F 50
#define HID 128

#define NPART 8
#define PART_NODES ((N_NODES + NPART - 1) / NPART)   // 12500

typedef __attribute__((ext_vector_type(8))) short bf16x8;
typedef __attribute__((ext_vector_type(4))) float f32x4;

__device__ __forceinline__ float bf2f(unsigned short s) {
    return __uint_as_float(((unsigned)s) << 16);
}
__device__ __forceinline__ unsigned short f2bf(float f) {
    unsigned u = __float_as_uint(f);
    u = (u + 0x7FFFu + ((u >> 16) & 1u)) >> 16;   // round-to-nearest-even
    return (unsigned short)u;
}

// ---------------- fused prep: zero deg | xconv | wconv | graph_ranges ----------------
#define PREP_W2 (N_NODES * 64)                  // xconv domain (6.4M)
#define PREP_W0 N_NODES                         // deg zero
#define PREP_W1 (128 * 64 + 128 * 128)          // wconv domain
#define PREP_W3 (N_GRAPHS + 1)                  // graph_ranges
#define PREP_TOTAL (PREP_W2 + PREP_W0 + PREP_W1 + PREP_W3)

__global__ __launch_bounds__(256) void prep_all(
    const float* __restrict__ x, unsigned short* __restrict__ xbf,
    int* __restrict__ deg,
    const float* __restrict__ Wr1, const float* __restrict__ Wo1,
    const float* __restrict__ Wr2, const float* __restrict__ Wo2,
    const float* __restrict__ Wr3, const float* __restrict__ Wo3,
    unsigned short* __restrict__ o_r1, unsigned short* __restrict__ o_o1,
    unsigned short* __restrict__ o_r2, unsigned short* __restrict__ o_o2,
    unsigned short* __restrict__ o_r3, unsigned short* __restrict__ o_o3,
    const int* __restrict__ batch, int* __restrict__ gstart) {
    int idx = blockIdx.x * 256 + threadIdx.x;
    if (idx < PREP_W2) {                         // xconv: x[100k][50] f32 -> xbf[100k][64] bf16
        int n = idx >> 6, c = idx & 63;
        float v = (c < IN_F) ? x[(size_t)n * IN_F + c] : 0.f;
        xbf[idx] = f2bf(v);
        return;
    }
    idx -= PREP_W2;
    if (idx < PREP_W0) { deg[idx] = 0; return; } // zero degree array
    idx -= PREP_W0;
    if (idx < PREP_W1) {                         // weight f32 -> bf16 (layer1 padded 50->64)
        if (idx < 128 * 64) {
            int n = idx >> 6, k = idx & 63;
            unsigned short a = 0, b = 0;
            if (k < IN_F) { a = f2bf(Wr1[n * IN_F + k]); b = f2bf(Wo1[n * IN_F + k]); }
            o_r1[idx] = a; o_o1[idx] = b;
        } else {
            int i2 = idx - 128 * 64;
            o_r2[i2] = f2bf(Wr2[i2]); o_o2[i2] = f2bf(Wo2[i2]);
            o_r3[i2] = f2bf(Wr3[i2]); o_o3[i2] = f2bf(Wo3[i2]);
        }
        return;
    }
    idx -= PREP_W1;
    if (idx < PREP_W3) {                         // graph_ranges (batch sorted)
        if (idx == N_GRAPHS) { gstart[idx] = N_NODES; return; }
        int lo = 0, hi = N_NODES;
        while (lo < hi) { int m = (lo + hi) >> 1; if (batch[m] < idx) lo = m + 1; else hi = m; }
        gstart[idx] = lo;
    }
}

// ---------------- CSR build (dst-partitioned for XCD write locality) ----------------
__global__ __launch_bounds__(256) void deg_hist(const int* __restrict__ dst,
                                                int* __restrict__ deg) {
    int part = blockIdx.x & (NPART - 1);
    int plo = part * PART_NODES, phi = plo + PART_NODES;
    int base = (blockIdx.x >> 3) * 256 + threadIdx.x;
    int stride = (gridDim.x >> 3) * 256;
    for (int e = base; e < N_EDGES; e += stride) {
        int d = dst[e];
        if (d >= plo && d < phi) atomicAdd(&deg[d], 1);
    }
}

__global__ __launch_bounds__(256) void csr_fill(const int* __restrict__ src,
                                                const int* __restrict__ dst,
                                                int* __restrict__ cursor,
                                                int* __restrict__ csr_src) {
    int part = blockIdx.x & (NPART - 1);
    int plo = part * PART_NODES, phi = plo + PART_NODES;
    int base = (blockIdx.x >> 3) * 256 + threadIdx.x;
    int stride = (gridDim.x >> 3) * 256;
    for (int e = base; e < N_EDGES; e += stride) {
        int d = dst[e];
        if (d >= plo && d < phi) {
            int p = atomicAdd(&cursor[d], 1);
            csr_src[p] = src[e];
        }
    }
}

// -------- 3-phase grid-wide exclusive scan of deg[100000] --------
#define SCAN_BLOCKS ((N_NODES + 1023) / 1024)   // 98

__global__ __launch_bounds__(256) void scan_phase1(const int* __restrict__ deg,
                                                   int* __restrict__ blocksum) {
    __shared__ int red[256];
    int b = blockIdx.x, t = threadIdx.x;
    int base = b * 1024 + t * 4;
    int s = 0;
#pragma unroll
    for (int i = 0; i < 4; i++) { int idx = base + i; if (idx < N_NODES) s += deg[idx]; }
    red[t] = s;
    __syncthreads();
    for (int off = 128; off > 0; off >>= 1) {
        if (t < off) red[t] += red[t + off];
        __syncthreads();
    }
    if (t == 0) blocksum[b] = red[0];
}

__global__ __launch_bounds__(128) void scan_phase2(const int* __restrict__ blocksum,
                                                   int* __restrict__ blockoff) {
    __shared__ int v[SCAN_BLOCKS];
    int t = threadIdx.x;
    if (t < SCAN_BLOCKS) v[t] = blocksum[t];
    __syncthreads();
    if (t == 0) {
        int run = 0;
        for (int i = 0; i < SCAN_BLOCKS; i++) { blockoff[i] = run; run += v[i]; }
        blockoff[SCAN_BLOCKS] = run;
    }
}

__global__ __launch_bounds__(256) void scan_phase3(const int* __restrict__ deg,
                                                   const int* __restrict__ blockoff,
                                                   int* __restrict__ rowptr,
                                                   int* __restrict__ cursor) {
    __shared__ int red[256];
    int b = blockIdx.x, t = threadIdx.x;
    int base = b * 1024 + t * 4;
    int e[4];
    int s = 0;
#pragma unroll
    for (int i = 0; i < 4; i++) {
        int idx = base + i;
        e[i] = (idx < N_NODES) ? deg[idx] : 0;
        s += e[i];
    }
    red[t] = s;
    __syncthreads();
    for (int off = 1; off < 256; off <<= 1) {
        int u = (t >= off) ? red[t - off] : 0;
        __syncthreads();
        red[t] += u;
        __syncthreads();
    }
    int prefix = red[t] - s + blockoff[b];
#pragma unroll
    for (int i = 0; i < 4; i++) {
        int idx = base + i;
        if (idx < N_NODES) { rowptr[idx] = prefix; cursor[idx] = prefix; prefix += e[i]; }
    }
    if (b == 0 && t == 0) rowptr[N_NODES] = blockoff[SCAN_BLOCKS];
}

// ---------------- pull aggregation ----------------
// layer 1: quarter-wave (16 lanes x uint2 = 128B row) per node, xbf [100k][64] bf16
__global__ __launch_bounds__(256) void gather_x64(const unsigned short* __restrict__ xbf,
                                                  const int* __restrict__ rowptr,
                                                  const int* __restrict__ csr_src,
                                                  unsigned short* __restrict__ aggbf) {
    int gid = blockIdx.x * 256 + threadIdx.x;
    int n = gid >> 4;
    int c = threadIdx.x & 15;
    if (n >= N_NODES) return;
    int jb = rowptr[n], je = rowptr[n + 1];
    const uint2* hu = reinterpret_cast<const uint2*>(xbf);
    float a0 = 0.f, a1 = 0.f, a2 = 0.f, a3 = 0.f;
    int j = jb;
    for (; j + 3 < je; j += 4) {
        int s0 = csr_src[j], s1 = csr_src[j + 1], s2 = csr_src[j + 2], s3 = csr_src[j + 3];
        uint2 v0 = hu[(size_t)s0 * 16 + c];
        uint2 v1 = hu[(size_t)s1 * 16 + c];
        uint2 v2 = hu[(size_t)s2 * 16 + c];
        uint2 v3 = hu[(size_t)s3 * 16 + c];
        a0 += (bf2f(v0.x & 0xFFFF) + bf2f(v1.x & 0xFFFF)) + (bf2f(v2.x & 0xFFFF) + bf2f(v3.x & 0xFFFF));
        a1 += (bf2f(v0.x >> 16) + bf2f(v1.x >> 16)) + (bf2f(v2.x >> 16) + bf2f(v3.x >> 16));
        a2 += (bf2f(v0.y & 0xFFFF) + bf2f(v1.y & 0xFFFF)) + (bf2f(v2.y & 0xFFFF) + bf2f(v3.y & 0xFFFF));
        a3 += (bf2f(v0.y >> 16) + bf2f(v1.y >> 16)) + (bf2f(v2.y >> 16) + bf2f(v3.y >> 16));
    }
    for (; j < je; j++) {
        int s0 = csr_src[j];
        uint2 v0 = hu[(size_t)s0 * 16 + c];
        a0 += bf2f(v0.x & 0xFFFF);
        a1 += bf2f(v0.x >> 16);
        a2 += bf2f(v0.y & 0xFFFF);
        a3 += bf2f(v0.y >> 16);
    }
    uint2 pk;
    pk.x = (unsigned)f2bf(a0) | ((unsigned)f2bf(a1) << 16);
    pk.y = (unsigned)f2bf(a2) | ((unsigned)f2bf(a3) << 16);
    reinterpret_cast<uint2*>(aggbf)[(size_t)n * 16 + c] = pk;
}

// layers 2/3: half-wave (32 lanes x uint2 = 256B row) per node, h [100k][128] bf16.
// One wave load instruction services 2 edges (2 rows) -> half the load-issue count
// vs wave-per-node dword layout (was 70.6us, transaction-bound component).
__global__ __launch_bounds__(256) void gather_bf128(const unsigned short* __restrict__ h,
                                                    const int* __restrict__ rowptr,
                                                    const int* __restrict__ csr_src,
                                                    unsigned short* __restrict__ aggbf) {
    int gid = blockIdx.x * 256 + threadIdx.x;
    int n = gid >> 5;
    int c = threadIdx.x & 31;
    if (n >= N_NODES) return;
    int jb = rowptr[n], je = rowptr[n + 1];
    const uint2* hu = reinterpret_cast<const uint2*>(h);
    float a0 = 0.f, a1 = 0.f, a2 = 0.f, a3 = 0.f;
    int j = jb;
    for (; j + 3 < je; j += 4) {
        int s0 = csr_src[j], s1 = csr_src[j + 1], s2 = csr_src[j + 2], s3 = csr_src[j + 3];
        uint2 v0 = hu[(size_t)s0 * 32 + c];
        uint2 v1 = hu[(size_t)s1 * 32 + c];
        uint2 v2 = hu[(size_t)s2 * 32 + c];
        uint2 v3 = hu[(size_t)s3 * 32 + c];
        a0 += (bf2f(v0.x & 0xFFFF) + bf2f(v1.x & 0xFFFF)) + (bf2f(v2.x & 0xFFFF) + bf2f(v3.x & 0xFFFF));
        a1 += (bf2f(v0.x >> 16) + bf2f(v1.x >> 16)) + (bf2f(v2.x >> 16) + bf2f(v3.x >> 16));
        a2 += (bf2f(v0.y & 0xFFFF) + bf2f(v1.y & 0xFFFF)) + (bf2f(v2.y & 0xFFFF) + bf2f(v3.y & 0xFFFF));
        a3 += (bf2f(v0.y >> 16) + bf2f(v1.y >> 16)) + (bf2f(v2.y >> 16) + bf2f(v3.y >> 16));
    }
    for (; j < je; j++) {
        int s0 = csr_src[j];
        uint2 v0 = hu[(size_t)s0 * 32 + c];
        a0 += bf2f(v0.x & 0xFFFF);
        a1 += bf2f(v0.x >> 16);
        a2 += bf2f(v0.y & 0xFFFF);
        a3 += bf2f(v0.y >> 16);
    }
    uint2 pk;
    pk.x = (unsigned)f2bf(a0) | ((unsigned)f2bf(a1) << 16);
    pk.y = (unsigned)f2bf(a2) | ((unsigned)f2bf(a3) << 16);
    reinterpret_cast<uint2*>(aggbf)[(size_t)n * 32 + c] = pk;
}

// ---------------- MFMA fused linear (no atomics) ----------------
// out = [relu](A1 @ B1^T + bias + A2 @ B2^T), stored bf16. A bf16 [M][K], B bf16 [128][K].
// Block = 256 thr = 4 waves; BM=128 (wave owns 32 rows = 2 m-tiles). Weights in LDS,
// PITCH = K*2+16. Operands swapped in MFMA: D = W_frag x A_frag -> lane&15 = node,
// (lane>>4)*4+reg = 4 consecutive out cols -> uint2 contiguous stores.
// In-place safe (hout may alias A1 or A2).
template <int K1, int K2, bool RELU>
__global__ __launch_bounds__(256) void mfma_linear(
    const unsigned short* __restrict__ A1, const unsigned short* __restrict__ A2,
    const unsigned short* __restrict__ B1, const unsigned short* __restrict__ B2,
    const float* __restrict__ bias, unsigned short* __restrict__ hout) {
    constexpr int P1 = K1 * 2 + 16;
    constexpr int P2 = K2 * 2 + 16;
    constexpr int PMAX = (P1 > P2 ? P1 : P2);
    __shared__ __align__(16) unsigned char ldsb[128 * PMAX];

    const int tid = threadIdx.x;
    const int lane = tid & 63;
    const int wave = tid >> 6;
    const int ar = lane & 15;
    const int kh = lane >> 4;
    const int m0 = blockIdx.x * 128 + wave * 32;

    f32x4 acc0[8], acc1[8];
#pragma unroll
    for (int nt = 0; nt < 8; nt++) {
        acc0[nt] = (f32x4){0.f, 0.f, 0.f, 0.f};
        acc1[nt] = (f32x4){0.f, 0.f, 0.f, 0.f};
    }

    int r0 = m0 + ar;      if (r0 > N_NODES - 1) r0 = N_NODES - 1;
    int r1 = m0 + 16 + ar; if (r1 > N_NODES - 1) r1 = N_NODES - 1;

    // ---- stage B1 ----
    {
        constexpr int CPR = K1 / 8;
#pragma unroll
        for (int ci = 0; ci < 128 * CPR / 256; ci++) {
            int c = ci * 256 + tid;
            int n = c / CPR, slot = c - n * CPR;
            uint4 v = *reinterpret_cast<const uint4*>(B1 + n * K1 + slot * 8);
            *reinterpret_cast<uint4*>(&ldsb[n * P1 + slot * 16]) = v;
        }
    }
    __syncthreads();
    // ---- K-loop 1 ----
    {
        const unsigned short* a0p = A1 + (size_t)r0 * K1 + kh * 8;
        const unsigned short* a1p = A1 + (size_t)r1 * K1 + kh * 8;
#pragma unroll
        for (int ks = 0; ks < K1 / 32; ks++) {
            bf16x8 a0 = *reinterpret_cast<const bf16x8*>(a0p + ks * 32);
            bf16x8 a1 = *reinterpret_cast<const bf16x8*>(a1p + ks * 32);
#pragma unroll
            for (int nt = 0; nt < 8; nt++) {
                bf16x8 b = *reinterpret_cast<const bf16x8*>(
                    &ldsb[(nt * 16 + ar) * P1 + ks * 64 + kh * 16]);
                acc0[nt] = __builtin_amdgcn_mfma_f32_16x16x32_bf16(b, a0, acc0[nt], 0, 0, 0);
                acc1[nt] = __builtin_amdgcn_mfma_f32_16x16x32_bf16(b, a1, acc1[nt], 0, 0, 0);
            }
        }
    }
    __syncthreads();
    // ---- stage B2 ----
    {
        constexpr int CPR = K2 / 8;
#pragma unroll
        for (int ci = 0; ci < 128 * CPR / 256; ci++) {
            int c = ci * 256 + tid;
            int n = c / CPR, slot = c - n * CPR;
            uint4 v = *reinterpret_cast<const uint4*>(B2 + n * K2 + slot * 8);
            *reinterpret_cast<uint4*>(&ldsb[n * P2 + slot * 16]) = v;
        }
    }
    __syncthreads();
    // ---- K-loop 2 ----
    {
        const unsigned short* a0p = A2 + (size_t)r0 * K2 + kh * 8;
        const unsigned short* a1p = A2 + (size_t)r1 * K2 + kh * 8;
#pragma unroll
        for (int ks = 0; ks < K2 / 32; ks++) {
            bf16x8 a0 = *reinterpret_cast<const bf16x8*>(a0p + ks * 32);
            bf16x8 a1 = *reinterpret_cast<const bf16x8*>(a1p + ks * 32);
#pragma unroll
            for (int nt = 0; nt < 8; nt++) {
                bf16x8 b = *reinterpret_cast<const bf16x8*>(
                    &ldsb[(nt * 16 + ar) * P2 + ks * 64 + kh * 16]);
                acc0[nt] = __builtin_amdgcn_mfma_f32_16x16x32_bf16(b, a0, acc0[nt], 0, 0, 0);
                acc1[nt] = __builtin_amdgcn_mfma_f32_16x16x32_bf16(b, a1, acc1[nt], 0, 0, 0);
            }
        }
    }

    // ---- epilogue ----
    float4 bv[8];
#pragma unroll
    for (int nt = 0; nt < 8; nt++)
        bv[nt] = *reinterpret_cast<const float4*>(bias + nt * 16 + kh * 4);

    int node0 = m0 + ar;
    int node1 = m0 + 16 + ar;
    if (node0 < N_NODES) {
#pragma unroll
        for (int nt = 0; nt < 8; nt++) {
            float v0 = acc0[nt][0] + bv[nt].x;
            float v1 = acc0[nt][1] + bv[nt].y;
            float v2 = acc0[nt][2] + bv[nt].z;
            float v3 = acc0[nt][3] + bv[nt].w;
            if (RELU) { v0 = fmaxf(v0, 0.f); v1 = fmaxf(v1, 0.f); v2 = fmaxf(v2, 0.f); v3 = fmaxf(v3, 0.f); }
            uint2 pk;
            pk.x = (unsigned)f2bf(v0) | ((unsigned)f2bf(v1) << 16);
            pk.y = (unsigned)f2bf(v2) | ((unsigned)f2bf(v3) << 16);
            *reinterpret_cast<uint2*>(hout + (size_t)node0 * HID + nt * 16 + kh * 4) = pk;
        }
    }
    if (node1 < N_NODES) {
#pragma unroll
        for (int nt = 0; nt < 8; nt++) {
            float v0 = acc1[nt][0] + bv[nt].x;
            float v1 = acc1[nt][1] + bv[nt].y;
            float v2 = acc1[nt][2] + bv[nt].z;
            float v3 = acc1[nt][3] + bv[nt].w;
            if (RELU) { v0 = fmaxf(v0, 0.f); v1 = fmaxf(v1, 0.f); v2 = fmaxf(v2, 0.f); v3 = fmaxf(v3, 0.f); }
            uint2 pk;
            pk.x = (unsigned)f2bf(v0) | ((unsigned)f2bf(v1) << 16);
            pk.y = (unsigned)f2bf(v2) | ((unsigned)f2bf(v3) << 16);
            *reinterpret_cast<uint2*>(hout + (size_t)node1 * HID + nt * 16 + kh * 4) = pk;
        }
    }
}

// ---------------- fused mean-pool + final linear (atomic-free) ----------------
__global__ __launch_bounds__(256) void pool_final(const unsigned short* __restrict__ h3,
                                                  const int* __restrict__ gstart,
                                                  const float* __restrict__ W_lin,
                                                  const float* __restrict__ b_lin,
                                                  float* __restrict__ out) {
    __shared__ float pp[4][HID];
    int g = blockIdx.x, t = threadIdx.x;
    int wave = t >> 6, lane = t & 63;
    int s0 = gstart[g], s1 = gstart[g + 1];
    const unsigned* h3u = reinterpret_cast<const unsigned*>(h3);
    float a0 = 0.f, a1 = 0.f;
    for (int n = s0 + wave; n < s1; n += 4) {
        unsigned v = h3u[(size_t)n * 64 + lane];
        a0 += bf2f((unsigned short)(v & 0xFFFF));
        a1 += bf2f((unsigned short)(v >> 16));
    }
    pp[wave][2 * lane] = a0;
    pp[wave][2 * lane + 1] = a1;
    __syncthreads();
    if (wave == 0) {
        float c = fmaxf((float)(s1 - s0), 1.f);
        float r0 = ((pp[0][2 * lane] + pp[1][2 * lane]) + (pp[2][2 * lane] + pp[3][2 * lane])) / c;
        float r1 = ((pp[0][2 * lane + 1] + pp[1][2 * lane + 1]) + (pp[2][2 * lane + 1] + pp[3][2 * lane + 1])) / c;
        pp[0][2 * lane] = r0;
        pp[0][2 * lane + 1] = r1;
    }
    __syncthreads();
    if (t < 4) {
        float s = b_lin[t];
#pragma unroll 8
        for (int k = 0; k < HID; k++) s += pp[0][k] * W_lin[t * HID + k];
        out[g * 4 + t] = s;
    }
}

extern "C" void kernel_launch(void* const* d_in, const int* in_sizes, int n_in,
                              void* d_out, int out_size, void* d_ws, size_t ws_size,
                              hipStream_t stream) {
    (void)in_sizes; (void)n_in; (void)out_size; (void)ws_size;
    const float* x      = (const float*)d_in[0];
    const int*   ei     = (const int*)d_in[1];
    const int*   batch  = (const int*)d_in[2];
    const float* W_rel1 = (const float*)d_in[3];
    const float* b_rel1 = (const float*)d_in[4];
    const float* W_root1= (const float*)d_in[5];
    const float* W_rel2 = (const float*)d_in[6];
    const float* b_rel2 = (const float*)d_in[7];
    const float* W_root2= (const float*)d_in[8];
    const float* W_rel3 = (const float*)d_in[9];
    const float* b_rel3 = (const float*)d_in[10];
    const float* W_root3= (const float*)d_in[11];
    const float* W_lin  = (const float*)d_in[12];
    const float* b_lin  = (const float*)d_in[13];
    const int* src = ei;
    const int* dst = ei + N_EDGES;

    char* ws = (char*)d_ws;
    size_t off = 0;
    auto alloc = [&](size_t bytes) { void* p = ws + off; off += (bytes + 255) & ~(size_t)255; return p; };
    unsigned short* aggbf    = (unsigned short*)alloc((size_t)N_NODES * HID * 2); // layer1 [.][64] slice; layer3 h3 in-place
    unsigned short* h1       = (unsigned short*)alloc((size_t)N_NODES * HID * 2); // layer 2 in-place
    unsigned short* xbf      = (unsigned short*)alloc((size_t)N_NODES * 64 * 2);
    int*            deg      = (int*)alloc((size_t)N_NODES * 4);
    int*            rowptr   = (int*)alloc((size_t)(N_NODES + 1) * 4);
    int*            cursor   = (int*)alloc((size_t)N_NODES * 4);
    int*            csr_src  = (int*)alloc((size_t)N_EDGES * 4);
    int*            blocksum = (int*)alloc((size_t)(SCAN_BLOCKS + 1) * 4);
    int*            blockoff = (int*)alloc((size_t)(SCAN_BLOCKS + 1) * 4);
    int*            gstart   = (int*)alloc((size_t)(N_GRAPHS + 1) * 4);
    unsigned short* Wb_rel1  = (unsigned short*)alloc(128 * 64 * 2);
    unsigned short* Wb_root1 = (unsigned short*)alloc(128 * 64 * 2);
    unsigned short* Wb_rel2  = (unsigned short*)alloc(128 * 128 * 2);
    unsigned short* Wb_root2 = (unsigned short*)alloc(128 * 128 * 2);
    unsigned short* Wb_rel3  = (unsigned short*)alloc(128 * 128 * 2);
    unsigned short* Wb_root3 = (unsigned short*)alloc(128 * 128 * 2);

    // ---- fused prep (zero deg | xconv | wconv | graph_ranges)
    prep_all<<<(PREP_TOTAL + 255) / 256, 256, 0, stream>>>(
        x, xbf, deg, W_rel1, W_root1, W_rel2, W_root2, W_rel3, W_root3,
        Wb_rel1, Wb_root1, Wb_rel2, Wb_root2, Wb_rel3, Wb_root3, batch, gstart);

    // ---- CSR build (dst-partitioned hist/fill, parallel scan)
    deg_hist<<<2048, 256, 0, stream>>>(dst, deg);
    scan_phase1<<<SCAN_BLOCKS, 256, 0, stream>>>(deg, blocksum);
    scan_phase2<<<1, 128, 0, stream>>>(blocksum, blockoff);
    scan_phase3<<<SCAN_BLOCKS, 256, 0, stream>>>(deg, blockoff, rowptr, cursor);
    csr_fill<<<2048, 256, 0, stream>>>(src, dst, cursor, csr_src);

    const int MFMA_BLOCKS = (N_NODES + 127) / 128;   // BM=128

    // ---- layer 1: pull-aggregate xbf (bf16, 128B rows), MFMA + relu -> h1
    gather_x64<<<(N_NODES * 16 + 255) / 256, 256, 0, stream>>>(xbf, rowptr, csr_src, aggbf);
    mfma_linear<64, 64, true><<<MFMA_BLOCKS, 256, 0, stream>>>(
        aggbf, xbf, Wb_rel1, Wb_root1, b_rel1, h1);

    // ---- layer 2: pull-aggregate h1, MFMA + relu -> h1 (in-place)
    gather_bf128<<<(N_NODES * 32 + 255) / 256, 256, 0, stream>>>(h1, rowptr, csr_src, aggbf);
    mfma_linear<128, 128, true><<<MFMA_BLOCKS, 256, 0, stream>>>(
        aggbf, h1, Wb_rel2, Wb_root2, b_rel2, h1);

    // ---- layer 3: pull-aggregate h1, MFMA (no relu) -> h3 (in-place over aggbf)
    gather_bf128<<<(N_NODES * 32 + 255) / 256, 256, 0, stream>>>(h1, rowptr, csr_src, aggbf);
    mfma_linear<128, 128, false><<<MFMA_BLOCKS, 256, 0, stream>>>(
        aggbf, h1, Wb_rel3, Wb_root3, b_rel3, aggbf);

    // ---- atomic-free mean-pool + final linear
    pool_final<<<N_GRAPHS, 256, 0, stream>>>(aggbf, gstart, W_lin, b_lin, (float*)d_out);
}